// Round 9
// baseline (170.186 us; speedup 1.0000x reference)
//
#include <hip/hip_runtime.h>
#include <hip/hip_bf16.h>
#include <stdint.h>

typedef unsigned short u16;
typedef __attribute__((ext_vector_type(8))) short short8;
typedef __attribute__((ext_vector_type(4))) float f32x4;

__device__ __forceinline__ u16 f2bf(float f) {
    union { float f; unsigned int i; } v; v.f = f;
    unsigned int b = v.i;
    return (u16)((b + 0x7FFFu + ((b >> 16) & 1u)) >> 16);
}

__device__ __forceinline__ short8 cvt8(float4 a, float4 b) {
    union { __hip_bfloat162 h[4]; short8 s; } u;
    u.h[0] = __float22bfloat162_rn(make_float2(a.x, a.y));
    u.h[1] = __float22bfloat162_rn(make_float2(a.z, a.w));
    u.h[2] = __float22bfloat162_rn(make_float2(b.x, b.y));
    u.h[3] = __float22bfloat162_rn(make_float2(b.z, b.w));
    return u.s;
}

typedef const __attribute__((address_space(1))) void* as1cv;
typedef __attribute__((address_space(3))) void* as3v;
__device__ __forceinline__ void gload16(const void* g, void* l) {
    __builtin_amdgcn_global_load_lds((as1cv)g, (as3v)l, 16, 0, 0);
}

__device__ __forceinline__ void up2(unsigned int v, float& lo, float& hi) {
    union { unsigned int i; float f; } a, b;
    a.i = v << 16; b.i = v & 0xffff0000u;
    lo = a.f; hi = b.f;
}

// ---------------------------------------------------------------------------
// wprep: weight convert fp32 -> bf16, transposed: Wt[n][k] = W[k][n]
// ---------------------------------------------------------------------------
__global__ __launch_bounds__(256) void wprep(
    const float* __restrict__ W0, const float* __restrict__ W1,
    const float* __restrict__ W2, const float* __restrict__ W3,
    u16* __restrict__ T0, u16* __restrict__ T1,
    u16* __restrict__ T2, u16* __restrict__ T3)
{
    const float* W = blockIdx.z == 0 ? W0 : blockIdx.z == 1 ? W1 : blockIdx.z == 2 ? W2 : W3;
    u16*        T  = blockIdx.z == 0 ? T0 : blockIdx.z == 1 ? T1 : blockIdx.z == 2 ? T2 : T3;
    __shared__ u16 ts[64][65];
    int k0 = blockIdx.x * 64, n0 = blockIdx.y * 64;
    int t = threadIdx.x;
    int r = t >> 2, cq = (t & 3) * 16;
    const float4* src = reinterpret_cast<const float4*>(W + (k0 + r) * 256 + n0 + cq);
    for (int u = 0; u < 4; ++u) {
        float4 v = src[u];
        int c = cq + u * 4;
        ts[r][c + 0] = f2bf(v.x); ts[r][c + 1] = f2bf(v.y);
        ts[r][c + 2] = f2bf(v.z); ts[r][c + 3] = f2bf(v.w);
    }
    __syncthreads();
    u16* dst = T + (n0 + r) * 256 + k0 + cq;
    for (int u = 0; u < 16; ++u) dst[u] = ts[cq + u][r];
}

// ---------------------------------------------------------------------------
// gemm_proj v2: full-N tiles, fused K->{Kh,Vh}. Tile 32 rows x 256 cols,
// block 256 (4 waves: rowgrp = (w>>1)*16, colhalf = (w&1)*128).
// z=0: Q @ Wtq -> Qh.  z=1: K @ {Wtk,Wtv} -> {Kh,Vh} (A staged ONCE).
// A fp32 staged via gload16 with XOR swizzle; cvt to bf16 at fragment read.
// grid (512, 2). LDS 8 + 32 + 32 = 72 KB.
// ---------------------------------------------------------------------------
__global__ __launch_bounds__(256) void gemm_proj(
    const float* __restrict__ Q, const float* __restrict__ K,
    const u16* __restrict__ Wtq, const u16* __restrict__ Wtk, const u16* __restrict__ Wtv,
    const float* __restrict__ bq, const float* __restrict__ bk, const float* __restrict__ bv,
    u16* __restrict__ Qh, u16* __restrict__ Kh, u16* __restrict__ Vh)
{
    int z = blockIdx.y;
    const float* Af  = z ? K   : Q;
    const u16*   Wt0 = z ? Wtk : Wtq;
    const float* bi0 = z ? bk  : bq;
    u16*         C0  = z ? Kh  : Qh;

    __shared__ float Asf[32 * 64];    // 8 KB
    __shared__ u16   B0s[256 * 64];   // 32 KB
    __shared__ u16   B1s[256 * 64];   // 32 KB (z==1 only)

    int t = threadIdx.x;
    int lane = t & 63, w = t >> 6;
    int row0 = blockIdx.x * 32;
    int rowgrp = (w >> 1) * 16, colh = (w & 1) * 128;
    int qd = lane >> 4, md = lane & 15;

    f32x4 acc0[8] = {};
    f32x4 acc1[8] = {};

    for (int kt = 0; kt < 256; kt += 64) {
        // A: 8 KB = 8 chunks; chunk = w*2+u
#pragma unroll
        for (int u = 0; u < 2; ++u) {
            int chunk = w * 2 + u;
            int s = chunk * 64 + lane;
            int r = s >> 4, c = s & 15;
            gload16(Af + (size_t)(row0 + r) * 256 + kt + ((c ^ (r & 15)) * 4),
                    (char*)Asf + chunk * 1024);
        }
        // B0: 32 KB = 32 chunks; chunk = w*8+u
#pragma unroll
        for (int u = 0; u < 8; ++u) {
            int chunk = w * 8 + u;
            int s = chunk * 64 + lane;
            int r = s >> 3, c = s & 7;
            gload16(Wt0 + (size_t)r * 256 + kt + ((c ^ (r & 7)) * 8),
                    (char*)B0s + chunk * 1024);
        }
        if (z) {
#pragma unroll
            for (int u = 0; u < 8; ++u) {
                int chunk = w * 8 + u;
                int s = chunk * 64 + lane;
                int r = s >> 3, c = s & 7;
                gload16(Wtv + (size_t)r * 256 + kt + ((c ^ (r & 7)) * 8),
                        (char*)B1s + chunk * 1024);
            }
        }
        __syncthreads();
#pragma unroll
        for (int ks = 0; ks < 64; ks += 32) {
            // A fragment (16 rows of this wave's rowgrp)
            int ar = rowgrp + md;
            int c0 = (ks >> 2) + qd * 2;
            int x = ar & 15;
            float4 fa0 = reinterpret_cast<const float4*>(Asf)[ar * 16 + (c0 ^ x)];
            float4 fa1 = reinterpret_cast<const float4*>(Asf)[ar * 16 + ((c0 + 1) ^ x)];
            short8 af = cvt8(fa0, fa1);
#pragma unroll
            for (int j = 0; j < 8; ++j) {
                int br = colh + j * 16 + md;
                int slot = ((ks >> 3) + qd) ^ (br & 7);
                short8 bf0 = reinterpret_cast<const short8*>(B0s)[br * 8 + slot];
                acc0[j] = __builtin_amdgcn_mfma_f32_16x16x32_bf16(af, bf0, acc0[j], 0, 0, 0);
                if (z) {
                    short8 bf1 = reinterpret_cast<const short8*>(B1s)[br * 8 + slot];
                    acc1[j] = __builtin_amdgcn_mfma_f32_16x16x32_bf16(af, bf1, acc1[j], 0, 0, 0);
                }
            }
        }
        __syncthreads();
    }

#pragma unroll
    for (int j = 0; j < 8; ++j) {
        int col = colh + j * 16 + md;
        float b0 = bi0[col];
        float b1 = z ? bv[col] : 0.f;
#pragma unroll
        for (int r = 0; r < 4; ++r) {
            int row = row0 + rowgrp + qd * 4 + r;
            C0[(size_t)row * 256 + col] = f2bf(acc0[j][r] + b0);
            if (z) Vh[(size_t)row * 256 + col] = f2bf(acc1[j][r] + b1);
        }
    }
}

// ---------------------------------------------------------------------------
// gemm_out: f32 C = bf16 A @ Wt^T + bias. 64x128 tile. (unchanged from R6)
// ---------------------------------------------------------------------------
__global__ __launch_bounds__(256) void gemm_out(
    const u16* __restrict__ Ab, const u16* __restrict__ Wt,
    const float* __restrict__ bias, float* __restrict__ Cout)
{
    __shared__ u16 As[64 * 64];
    __shared__ u16 Bs[128 * 64];

    int t = threadIdx.x;
    int lane = t & 63, w = t >> 6;
    int row0 = blockIdx.x * 64, col0 = blockIdx.y * 128;
    int wr = (w >> 1) * 32, wc = (w & 1) * 64;
    int qd = lane >> 4, md = lane & 15;

    f32x4 acc[2][4] = {};

    for (int kt = 0; kt < 256; kt += 64) {
#pragma unroll
        for (int u = 0; u < 2; ++u) {
            int chunk = w * 2 + u;
            int s = chunk * 64 + lane;
            int r = s >> 3, c = s & 7;
            gload16(Ab + (size_t)(row0 + r) * 256 + kt + ((c ^ (r & 7)) * 8),
                    (char*)As + chunk * 1024);
        }
#pragma unroll
        for (int u = 0; u < 4; ++u) {
            int chunk = w * 4 + u;
            int s = chunk * 64 + lane;
            int r = s >> 3, c = s & 7;
            gload16(Wt + (size_t)(col0 + r) * 256 + kt + ((c ^ (r & 7)) * 8),
                    (char*)Bs + chunk * 1024);
        }
        __syncthreads();
#pragma unroll
        for (int ks = 0; ks < 64; ks += 32) {
            short8 af[2], bf[4];
#pragma unroll
            for (int i = 0; i < 2; ++i) {
                int ar = wr + i * 16 + md;
                int slot = ((ks >> 3) + qd) ^ (ar & 7);
                af[i] = reinterpret_cast<const short8*>(As)[ar * 8 + slot];
            }
#pragma unroll
            for (int j = 0; j < 4; ++j) {
                int br = wc + j * 16 + md;
                int slot = ((ks >> 3) + qd) ^ (br & 7);
                bf[j] = reinterpret_cast<const short8*>(Bs)[br * 8 + slot];
            }
#pragma unroll
            for (int i = 0; i < 2; ++i)
#pragma unroll
                for (int j = 0; j < 4; ++j)
                    acc[i][j] = __builtin_amdgcn_mfma_f32_16x16x32_bf16(
                        af[i], bf[j], acc[i][j], 0, 0, 0);
        }
        __syncthreads();
    }

#pragma unroll
    for (int i = 0; i < 2; ++i)
#pragma unroll
        for (int j = 0; j < 4; ++j) {
            int col = col0 + wc + j * 16 + md;
            float b = bias[col];
#pragma unroll
            for (int r = 0; r < 4; ++r) {
                int row = row0 + wr + i * 16 + qd * 4 + r;
                Cout[(size_t)row * 256 + col] = acc[i][j][r] + b;
            }
        }
}

// ---------------------------------------------------------------------------
// attn v6: R7 layout + V-PREFETCH: all 16 V loads issued right after the 16
// K loads (V addresses known early), so K-consume + softmax overlap V latency.
// ---------------------------------------------------------------------------
__global__ __launch_bounds__(256) void attn(
    const u16* __restrict__ Qh, const u16* __restrict__ Kh, const u16* __restrict__ Vh,
    const int* __restrict__ nbr, u16* __restrict__ AVb)
{
    __shared__ int jbs[4][32];

    int t = threadIdx.x;
    int w = t >> 6, lane = t & 63;
    int row = blockIdx.x * 4 + w;
    int b = row >> 13;
    int bbase = b << 13;

    int c8 = lane & 31;
    int jh = lane >> 5;

    if (lane < 32) {
        int ji = nbr[(size_t)row * 32 + lane];
        jbs[w][lane] = (bbase + ji) * 256;
    }

    float qf[8];
    {
        uint4 qw = *reinterpret_cast<const uint4*>(Qh + (size_t)row * 256 + c8 * 8);
        up2(qw.x, qf[0], qf[1]); up2(qw.y, qf[2], qf[3]);
        up2(qw.z, qf[4], qf[5]); up2(qw.w, qf[6], qf[7]);
    }

    // issue ALL K loads, then ALL V loads (32 in flight), then consume
    uint4 kw[16], vv[16];
#pragma unroll
    for (int jj = 0; jj < 16; ++jj) {
        int off = jbs[w][jh * 16 + jj];
        kw[jj] = *reinterpret_cast<const uint4*>(Kh + (size_t)off + c8 * 8);
    }
#pragma unroll
    for (int jj = 0; jj < 16; ++jj) {
        int off = jbs[w][jh * 16 + jj];
        vv[jj] = *reinterpret_cast<const uint4*>(Vh + (size_t)off + c8 * 8);
    }

    float e16[16];
#pragma unroll
    for (int jj = 0; jj < 16; ++jj) {
        float k0, k1;
        float p = 0.f;
        up2(kw[jj].x, k0, k1); p = fmaf(qf[0], k0, p); p = fmaf(qf[1], k1, p);
        up2(kw[jj].y, k0, k1); p = fmaf(qf[2], k0, p); p = fmaf(qf[3], k1, p);
        up2(kw[jj].z, k0, k1); p = fmaf(qf[4], k0, p); p = fmaf(qf[5], k1, p);
        up2(kw[jj].w, k0, k1); p = fmaf(qf[6], k0, p); p = fmaf(qf[7], k1, p);
        p += __shfl_xor(p, 1);
        p += __shfl_xor(p, 2);
        e16[jj] = p * 0.0625f;
    }

    float m = e16[0];
#pragma unroll
    for (int jj = 1; jj < 16; ++jj) m = fmaxf(m, e16[jj]);
    m = fmaxf(m, __shfl_xor(m, 32));
    float s = 0.f;
#pragma unroll
    for (int jj = 0; jj < 16; ++jj) { e16[jj] = __expf(e16[jj] - m); s += e16[jj]; }
    s += __shfl_xor(s, 32);
    float rs = 1.0f / s;
#pragma unroll
    for (int jj = 0; jj < 16; ++jj) e16[jj] *= rs;

    float acc[8] = {};
#pragma unroll
    for (int jj = 0; jj < 16; ++jj) {
        float v0, v1;
        float wgt = e16[jj];
        up2(vv[jj].x, v0, v1); acc[0] = fmaf(wgt, v0, acc[0]); acc[1] = fmaf(wgt, v1, acc[1]);
        up2(vv[jj].y, v0, v1); acc[2] = fmaf(wgt, v0, acc[2]); acc[3] = fmaf(wgt, v1, acc[3]);
        up2(vv[jj].z, v0, v1); acc[4] = fmaf(wgt, v0, acc[4]); acc[5] = fmaf(wgt, v1, acc[5]);
        up2(vv[jj].w, v0, v1); acc[6] = fmaf(wgt, v0, acc[6]); acc[7] = fmaf(wgt, v1, acc[7]);
    }
#pragma unroll
    for (int u = 0; u < 8; ++u) acc[u] += __shfl_xor(acc[u], 32);

    if (lane < 32) {
        union { __hip_bfloat162 h[4]; uint4 u4; } o;
        o.h[0] = __float22bfloat162_rn(make_float2(acc[0], acc[1]));
        o.h[1] = __float22bfloat162_rn(make_float2(acc[2], acc[3]));
        o.h[2] = __float22bfloat162_rn(make_float2(acc[4], acc[5]));
        o.h[3] = __float22bfloat162_rn(make_float2(acc[6], acc[7]));
        *reinterpret_cast<uint4*>(AVb + (size_t)row * 256 + c8 * 8) = o.u4;
    }
}

// ---------------------------------------------------------------------------
extern "C" void kernel_launch(void* const* d_in, const int* in_sizes, int n_in,
                              void* d_out, int out_size, void* d_ws, size_t ws_size,
                              hipStream_t stream) {
    const float* Q   = (const float*)d_in[0];
    const float* K   = (const float*)d_in[1];
    const int*   nbr = (const int*)d_in[2];
    const float* Wq  = (const float*)d_in[3];
    const float* bq  = (const float*)d_in[4];
    const float* Wk  = (const float*)d_in[5];
    const float* bk  = (const float*)d_in[6];
    const float* Wv  = (const float*)d_in[7];
    const float* bv  = (const float*)d_in[8];
    const float* Wo  = (const float*)d_in[9];
    const float* bo  = (const float*)d_in[10];
    float* out = (float*)d_out;

    char* ws = (char*)d_ws;
    size_t off = 0;
    auto alloc = [&](size_t bytes) -> void* {
        void* p = ws + off;
        off += (bytes + 255) & ~(size_t)255;
        return p;
    };
    const size_t MN = 16384;
    u16* Wtq = (u16*)alloc(256 * 256 * 2);
    u16* Wtk = (u16*)alloc(256 * 256 * 2);
    u16* Wtv = (u16*)alloc(256 * 256 * 2);
    u16* Wto = (u16*)alloc(256 * 256 * 2);
    u16* Qh  = (u16*)alloc(MN * 256 * 2);
    u16* Kh  = (u16*)alloc(MN * 256 * 2);
    u16* Vh  = (u16*)alloc(MN * 256 * 2);
    u16* AVb = (u16*)alloc(MN * 256 * 2);

    wprep<<<dim3(4, 4, 4), 256, 0, stream>>>(Wq, Wk, Wv, Wo, Wtq, Wtk, Wtv, Wto);
    gemm_proj<<<dim3(512, 2), 256, 0, stream>>>(Q, K, Wtq, Wtk, Wtv,
                                                bq, bk, bv, Qh, Kh, Vh);
    attn<<<dim3(4096), 256, 0, stream>>>(Qh, Kh, Vh, nbr, AVb);
    gemm_out<<<dim3(256, 2), 256, 0, stream>>>(AVb, Wto, bo, out);
}

// Round 10
// 164.463 us; speedup vs baseline: 1.0348x; 1.0348x over previous
//
#include <hip/hip_runtime.h>
#include <hip/hip_bf16.h>
#include <stdint.h>

typedef unsigned short u16;
typedef __attribute__((ext_vector_type(8))) short short8;
typedef __attribute__((ext_vector_type(4))) float f32x4;

__device__ __forceinline__ u16 f2bf(float f) {
    union { float f; unsigned int i; } v; v.f = f;
    unsigned int b = v.i;
    return (u16)((b + 0x7FFFu + ((b >> 16) & 1u)) >> 16);
}

__device__ __forceinline__ short8 cvt8(float4 a, float4 b) {
    union { __hip_bfloat162 h[4]; short8 s; } u;
    u.h[0] = __float22bfloat162_rn(make_float2(a.x, a.y));
    u.h[1] = __float22bfloat162_rn(make_float2(a.z, a.w));
    u.h[2] = __float22bfloat162_rn(make_float2(b.x, b.y));
    u.h[3] = __float22bfloat162_rn(make_float2(b.z, b.w));
    return u.s;
}

typedef const __attribute__((address_space(1))) void* as1cv;
typedef __attribute__((address_space(3))) void* as3v;
__device__ __forceinline__ void gload16(const void* g, void* l) {
    __builtin_amdgcn_global_load_lds((as1cv)g, (as3v)l, 16, 0, 0);
}

__device__ __forceinline__ void up2(unsigned int v, float& lo, float& hi) {
    union { unsigned int i; float f; } a, b;
    a.i = v << 16; b.i = v & 0xffff0000u;
    lo = a.f; hi = b.f;
}

// ---------------------------------------------------------------------------
// wprep: weight convert fp32 -> bf16, transposed: Wt[n][k] = W[k][n]
// ---------------------------------------------------------------------------
__global__ __launch_bounds__(256) void wprep(
    const float* __restrict__ W0, const float* __restrict__ W1,
    const float* __restrict__ W2, const float* __restrict__ W3,
    u16* __restrict__ T0, u16* __restrict__ T1,
    u16* __restrict__ T2, u16* __restrict__ T3)
{
    const float* W = blockIdx.z == 0 ? W0 : blockIdx.z == 1 ? W1 : blockIdx.z == 2 ? W2 : W3;
    u16*        T  = blockIdx.z == 0 ? T0 : blockIdx.z == 1 ? T1 : blockIdx.z == 2 ? T2 : T3;
    __shared__ u16 ts[64][65];
    int k0 = blockIdx.x * 64, n0 = blockIdx.y * 64;
    int t = threadIdx.x;
    int r = t >> 2, cq = (t & 3) * 16;
    const float4* src = reinterpret_cast<const float4*>(W + (k0 + r) * 256 + n0 + cq);
    for (int u = 0; u < 4; ++u) {
        float4 v = src[u];
        int c = cq + u * 4;
        ts[r][c + 0] = f2bf(v.x); ts[r][c + 1] = f2bf(v.y);
        ts[r][c + 2] = f2bf(v.z); ts[r][c + 3] = f2bf(v.w);
    }
    __syncthreads();
    u16* dst = T + (n0 + r) * 256 + k0 + cq;
    for (int u = 0; u < 16; ++u) dst[u] = ts[cq + u][r];
}

// ---------------------------------------------------------------------------
// gemm_proj v3: full-N (y=1) tiles: 64 rows x 256 cols, BK=64, 4 waves,
// wave = 16 rows x 256 cols (acc 16 x f32x4). grid (256, 3):
// z=0: Q@Wtq->Qh, z=1: K@Wtk->Kh, z=2: K@Wtv->Vh.  Q read 1x, K read 2x.
// A staged fp32 via gload16 + XOR swizzle (16 KB); B bf16 (32 KB). 48 KB LDS.
// ---------------------------------------------------------------------------
__global__ __launch_bounds__(256) void gemm_proj(
    const float* __restrict__ Q, const float* __restrict__ K,
    const u16* __restrict__ Wtq, const u16* __restrict__ Wtk, const u16* __restrict__ Wtv,
    const float* __restrict__ bq, const float* __restrict__ bk, const float* __restrict__ bv,
    u16* __restrict__ Qh, u16* __restrict__ Kh, u16* __restrict__ Vh)
{
    int z = blockIdx.y;
    const float* Af   = (z == 0) ? Q   : K;
    const u16*   Wt   = (z == 0) ? Wtq : (z == 1) ? Wtk : Wtv;
    const float* bias = (z == 0) ? bq  : (z == 1) ? bk  : bv;
    u16*         C    = (z == 0) ? Qh  : (z == 1) ? Kh  : Vh;

    __shared__ float Asf[64 * 64];    // 16 KB
    __shared__ u16   Bs[256 * 64];    // 32 KB

    int t = threadIdx.x;
    int lane = t & 63, w = t >> 6;
    int row0 = blockIdx.x * 64;
    int qd = lane >> 4, md = lane & 15;

    f32x4 acc[16] = {};

    for (int kt = 0; kt < 256; kt += 64) {
        // A: 16 KB = 16 chunks of 1 KB; chunk = w*4+u
#pragma unroll
        for (int u = 0; u < 4; ++u) {
            int chunk = w * 4 + u;
            int s = chunk * 64 + lane;
            int r = s >> 4, c = s & 15;
            gload16(Af + (size_t)(row0 + r) * 256 + kt + ((c ^ (r & 15)) * 4),
                    (char*)Asf + chunk * 1024);
        }
        // B: 32 KB = 32 chunks; chunk = w*8+u (all 256 weight rows)
#pragma unroll
        for (int u = 0; u < 8; ++u) {
            int chunk = w * 8 + u;
            int s = chunk * 64 + lane;
            int r = s >> 3, c = s & 7;
            gload16(Wt + (size_t)r * 256 + kt + ((c ^ (r & 7)) * 8),
                    (char*)Bs + chunk * 1024);
        }
        __syncthreads();
#pragma unroll
        for (int ks = 0; ks < 64; ks += 32) {
            int ar = w * 16 + md;
            int c0 = (ks >> 2) + qd * 2;
            int x = ar & 15;
            float4 fa0 = reinterpret_cast<const float4*>(Asf)[ar * 16 + (c0 ^ x)];
            float4 fa1 = reinterpret_cast<const float4*>(Asf)[ar * 16 + ((c0 + 1) ^ x)];
            short8 af = cvt8(fa0, fa1);
#pragma unroll
            for (int j = 0; j < 16; ++j) {
                int br = j * 16 + md;
                int slot = ((ks >> 3) + qd) ^ (br & 7);
                short8 bf = reinterpret_cast<const short8*>(Bs)[br * 8 + slot];
                acc[j] = __builtin_amdgcn_mfma_f32_16x16x32_bf16(af, bf, acc[j], 0, 0, 0);
            }
        }
        __syncthreads();
    }

#pragma unroll
    for (int j = 0; j < 16; ++j) {
        int col = j * 16 + md;
        float b = bias[col];
#pragma unroll
        for (int r = 0; r < 4; ++r) {
            int row = row0 + w * 16 + qd * 4 + r;
            C[(size_t)row * 256 + col] = f2bf(acc[j][r] + b);
        }
    }
}

// ---------------------------------------------------------------------------
// gemm_out: f32 C = bf16 A @ Wt^T + bias. 64x128 tile. (unchanged from R6)
// ---------------------------------------------------------------------------
__global__ __launch_bounds__(256) void gemm_out(
    const u16* __restrict__ Ab, const u16* __restrict__ Wt,
    const float* __restrict__ bias, float* __restrict__ Cout)
{
    __shared__ u16 As[64 * 64];
    __shared__ u16 Bs[128 * 64];

    int t = threadIdx.x;
    int lane = t & 63, w = t >> 6;
    int row0 = blockIdx.x * 64, col0 = blockIdx.y * 128;
    int wr = (w >> 1) * 32, wc = (w & 1) * 64;
    int qd = lane >> 4, md = lane & 15;

    f32x4 acc[2][4] = {};

    for (int kt = 0; kt < 256; kt += 64) {
#pragma unroll
        for (int u = 0; u < 2; ++u) {
            int chunk = w * 2 + u;
            int s = chunk * 64 + lane;
            int r = s >> 3, c = s & 7;
            gload16(Ab + (size_t)(row0 + r) * 256 + kt + ((c ^ (r & 7)) * 8),
                    (char*)As + chunk * 1024);
        }
#pragma unroll
        for (int u = 0; u < 4; ++u) {
            int chunk = w * 4 + u;
            int s = chunk * 64 + lane;
            int r = s >> 3, c = s & 7;
            gload16(Wt + (size_t)(col0 + r) * 256 + kt + ((c ^ (r & 7)) * 8),
                    (char*)Bs + chunk * 1024);
        }
        __syncthreads();
#pragma unroll
        for (int ks = 0; ks < 64; ks += 32) {
            short8 af[2], bf[4];
#pragma unroll
            for (int i = 0; i < 2; ++i) {
                int ar = wr + i * 16 + md;
                int slot = ((ks >> 3) + qd) ^ (ar & 7);
                af[i] = reinterpret_cast<const short8*>(As)[ar * 8 + slot];
            }
#pragma unroll
            for (int j = 0; j < 4; ++j) {
                int br = wc + j * 16 + md;
                int slot = ((ks >> 3) + qd) ^ (br & 7);
                bf[j] = reinterpret_cast<const short8*>(Bs)[br * 8 + slot];
            }
#pragma unroll
            for (int i = 0; i < 2; ++i)
#pragma unroll
                for (int j = 0; j < 4; ++j)
                    acc[i][j] = __builtin_amdgcn_mfma_f32_16x16x32_bf16(
                        af[i], bf[j], acc[i][j], 0, 0, 0);
        }
        __syncthreads();
    }

#pragma unroll
    for (int i = 0; i < 2; ++i)
#pragma unroll
        for (int j = 0; j < 4; ++j) {
            int col = col0 + wc + j * 16 + md;
            float b = bias[col];
#pragma unroll
            for (int r = 0; r < 4; ++r) {
                int row = row0 + wr + i * 16 + qd * 4 + r;
                Cout[(size_t)row * 256 + col] = acc[i][j][r] + b;
            }
        }
}

// ---------------------------------------------------------------------------
// attn (exact R8 best): one wave per row, 2x8 batched K loads, register
// softmax, 2x8 batched V loads. 45.4 us measured.
// ---------------------------------------------------------------------------
__global__ __launch_bounds__(256) void attn(
    const u16* __restrict__ Qh, const u16* __restrict__ Kh, const u16* __restrict__ Vh,
    const int* __restrict__ nbr, u16* __restrict__ AVb)
{
    __shared__ int jbs[4][32];

    int t = threadIdx.x;
    int w = t >> 6, lane = t & 63;
    int row = blockIdx.x * 4 + w;
    int b = row >> 13;
    int bbase = b << 13;

    int c8 = lane & 31;
    int jh = lane >> 5;

    if (lane < 32) {
        int ji = nbr[(size_t)row * 32 + lane];
        jbs[w][lane] = (bbase + ji) * 256;
    }

    float qf[8];
    {
        uint4 qw = *reinterpret_cast<const uint4*>(Qh + (size_t)row * 256 + c8 * 8);
        up2(qw.x, qf[0], qf[1]); up2(qw.y, qf[2], qf[3]);
        up2(qw.z, qf[4], qf[5]); up2(qw.w, qf[6], qf[7]);
    }

    float e16[16];
#pragma unroll
    for (int bb = 0; bb < 2; ++bb) {
        uint4 kw[8];
#pragma unroll
        for (int u = 0; u < 8; ++u) {
            int koff = jbs[w][jh * 16 + bb * 8 + u];
            kw[u] = *reinterpret_cast<const uint4*>(Kh + (size_t)koff + c8 * 8);
        }
#pragma unroll
        for (int u = 0; u < 8; ++u) {
            float k0, k1;
            float p = 0.f;
            up2(kw[u].x, k0, k1); p = fmaf(qf[0], k0, p); p = fmaf(qf[1], k1, p);
            up2(kw[u].y, k0, k1); p = fmaf(qf[2], k0, p); p = fmaf(qf[3], k1, p);
            up2(kw[u].z, k0, k1); p = fmaf(qf[4], k0, p); p = fmaf(qf[5], k1, p);
            up2(kw[u].w, k0, k1); p = fmaf(qf[6], k0, p); p = fmaf(qf[7], k1, p);
            p += __shfl_xor(p, 1);
            p += __shfl_xor(p, 2);
            e16[bb * 8 + u] = p * 0.0625f;
        }
    }

    float m = e16[0];
#pragma unroll
    for (int jj = 1; jj < 16; ++jj) m = fmaxf(m, e16[jj]);
    m = fmaxf(m, __shfl_xor(m, 32));
    float s = 0.f;
#pragma unroll
    for (int jj = 0; jj < 16; ++jj) { e16[jj] = __expf(e16[jj] - m); s += e16[jj]; }
    s += __shfl_xor(s, 32);
    float rs = 1.0f / s;
#pragma unroll
    for (int jj = 0; jj < 16; ++jj) e16[jj] *= rs;

    float acc[8] = {};
#pragma unroll
    for (int bb = 0; bb < 2; ++bb) {
        uint4 vv[8];
#pragma unroll
        for (int u = 0; u < 8; ++u) {
            int voff = jbs[w][jh * 16 + bb * 8 + u];
            vv[u] = *reinterpret_cast<const uint4*>(Vh + (size_t)voff + c8 * 8);
        }
#pragma unroll
        for (int u = 0; u < 8; ++u) {
            float v0, v1;
            float wgt = e16[bb * 8 + u];
            up2(vv[u].x, v0, v1); acc[0] = fmaf(wgt, v0, acc[0]); acc[1] = fmaf(wgt, v1, acc[1]);
            up2(vv[u].y, v0, v1); acc[2] = fmaf(wgt, v0, acc[2]); acc[3] = fmaf(wgt, v1, acc[3]);
            up2(vv[u].z, v0, v1); acc[4] = fmaf(wgt, v0, acc[4]); acc[5] = fmaf(wgt, v1, acc[5]);
            up2(vv[u].w, v0, v1); acc[6] = fmaf(wgt, v0, acc[6]); acc[7] = fmaf(wgt, v1, acc[7]);
        }
    }
#pragma unroll
    for (int u = 0; u < 8; ++u) acc[u] += __shfl_xor(acc[u], 32);

    if (lane < 32) {
        union { __hip_bfloat162 h[4]; uint4 u4; } o;
        o.h[0] = __float22bfloat162_rn(make_float2(acc[0], acc[1]));
        o.h[1] = __float22bfloat162_rn(make_float2(acc[2], acc[3]));
        o.h[2] = __float22bfloat162_rn(make_float2(acc[4], acc[5]));
        o.h[3] = __float22bfloat162_rn(make_float2(acc[6], acc[7]));
        *reinterpret_cast<uint4*>(AVb + (size_t)row * 256 + c8 * 8) = o.u4;
    }
}

// ---------------------------------------------------------------------------
extern "C" void kernel_launch(void* const* d_in, const int* in_sizes, int n_in,
                              void* d_out, int out_size, void* d_ws, size_t ws_size,
                              hipStream_t stream) {
    const float* Q   = (const float*)d_in[0];
    const float* K   = (const float*)d_in[1];
    const int*   nbr = (const int*)d_in[2];
    const float* Wq  = (const float*)d_in[3];
    const float* bq  = (const float*)d_in[4];
    const float* Wk  = (const float*)d_in[5];
    const float* bk  = (const float*)d_in[6];
    const float* Wv  = (const float*)d_in[7];
    const float* bv  = (const float*)d_in[8];
    const float* Wo  = (const float*)d_in[9];
    const float* bo  = (const float*)d_in[10];
    float* out = (float*)d_out;

    char* ws = (char*)d_ws;
    size_t off = 0;
    auto alloc = [&](size_t bytes) -> void* {
        void* p = ws + off;
        off += (bytes + 255) & ~(size_t)255;
        return p;
    };
    const size_t MN = 16384;
    u16* Wtq = (u16*)alloc(256 * 256 * 2);
    u16* Wtk = (u16*)alloc(256 * 256 * 2);
    u16* Wtv = (u16*)alloc(256 * 256 * 2);
    u16* Wto = (u16*)alloc(256 * 256 * 2);
    u16* Qh  = (u16*)alloc(MN * 256 * 2);
    u16* Kh  = (u16*)alloc(MN * 256 * 2);
    u16* Vh  = (u16*)alloc(MN * 256 * 2);
    u16* AVb = (u16*)alloc(MN * 256 * 2);

    wprep<<<dim3(4, 4, 4), 256, 0, stream>>>(Wq, Wk, Wv, Wo, Wtq, Wtk, Wtv, Wto);
    gemm_proj<<<dim3(256, 3), 256, 0, stream>>>(Q, K, Wtq, Wtk, Wtv,
                                                bq, bk, bv, Qh, Kh, Vh);
    attn<<<dim3(4096), 256, 0, stream>>>(Qh, Kh, Vh, nbr, AVb);
    gemm_out<<<dim3(256, 2), 256, 0, stream>>>(AVb, Wto, bo, out);
}

// Round 11
// 159.738 us; speedup vs baseline: 1.0654x; 1.0296x over previous
//
#include <hip/hip_runtime.h>
#include <hip/hip_bf16.h>
#include <stdint.h>

typedef unsigned short u16;
typedef __attribute__((ext_vector_type(8))) short short8;
typedef __attribute__((ext_vector_type(4))) float f32x4;

__device__ __forceinline__ u16 f2bf(float f) {
    union { float f; unsigned int i; } v; v.f = f;
    unsigned int b = v.i;
    return (u16)((b + 0x7FFFu + ((b >> 16) & 1u)) >> 16);
}

__device__ __forceinline__ short8 cvt8(float4 a, float4 b) {
    union { __hip_bfloat162 h[4]; short8 s; } u;
    u.h[0] = __float22bfloat162_rn(make_float2(a.x, a.y));
    u.h[1] = __float22bfloat162_rn(make_float2(a.z, a.w));
    u.h[2] = __float22bfloat162_rn(make_float2(b.x, b.y));
    u.h[3] = __float22bfloat162_rn(make_float2(b.z, b.w));
    return u.s;
}

typedef const __attribute__((address_space(1))) void* as1cv;
typedef __attribute__((address_space(3))) void* as3v;
__device__ __forceinline__ void gload16(const void* g, void* l) {
    __builtin_amdgcn_global_load_lds((as1cv)g, (as3v)l, 16, 0, 0);
}

__device__ __forceinline__ void up2(unsigned int v, float& lo, float& hi) {
    union { unsigned int i; float f; } a, b;
    a.i = v << 16; b.i = v & 0xffff0000u;
    lo = a.f; hi = b.f;
}

// ---------------------------------------------------------------------------
// wprep: weight convert fp32 -> bf16, transposed: Wt[n][k] = W[k][n]
// ---------------------------------------------------------------------------
__global__ __launch_bounds__(256) void wprep(
    const float* __restrict__ W0, const float* __restrict__ W1,
    const float* __restrict__ W2, const float* __restrict__ W3,
    u16* __restrict__ T0, u16* __restrict__ T1,
    u16* __restrict__ T2, u16* __restrict__ T3)
{
    const float* W = blockIdx.z == 0 ? W0 : blockIdx.z == 1 ? W1 : blockIdx.z == 2 ? W2 : W3;
    u16*        T  = blockIdx.z == 0 ? T0 : blockIdx.z == 1 ? T1 : blockIdx.z == 2 ? T2 : T3;
    __shared__ u16 ts[64][65];
    int k0 = blockIdx.x * 64, n0 = blockIdx.y * 64;
    int t = threadIdx.x;
    int r = t >> 2, cq = (t & 3) * 16;
    const float4* src = reinterpret_cast<const float4*>(W + (k0 + r) * 256 + n0 + cq);
    for (int u = 0; u < 4; ++u) {
        float4 v = src[u];
        int c = cq + u * 4;
        ts[r][c + 0] = f2bf(v.x); ts[r][c + 1] = f2bf(v.y);
        ts[r][c + 2] = f2bf(v.z); ts[r][c + 3] = f2bf(v.w);
    }
    __syncthreads();
    u16* dst = T + (n0 + r) * 256 + k0 + cq;
    for (int u = 0; u < 16; ++u) dst[u] = ts[cq + u][r];
}

// ---------------------------------------------------------------------------
// gemm_proj (best measured, R6/R7/R8): C_bf16 = cvt(A_fp32) @ Wt^T + bias.
// 128x128 tile, BK=64, XOR-swizzled LDS, global_load_lds staging. grid (128,2,3).
// ---------------------------------------------------------------------------
__global__ __launch_bounds__(256) void gemm_proj(
    const float* __restrict__ Q, const float* __restrict__ K,
    const u16* __restrict__ Wtq, const u16* __restrict__ Wtk, const u16* __restrict__ Wtv,
    const float* __restrict__ bq, const float* __restrict__ bk, const float* __restrict__ bv,
    u16* __restrict__ Qh, u16* __restrict__ Kh, u16* __restrict__ Vh)
{
    int z = blockIdx.z;
    const float* Af   = (z == 0) ? Q   : K;
    const u16*   Wt   = (z == 0) ? Wtq : (z == 1) ? Wtk : Wtv;
    const float* bias = (z == 0) ? bq  : (z == 1) ? bk  : bv;
    u16*         C    = (z == 0) ? Qh  : (z == 1) ? Kh  : Vh;

    __shared__ float Asf[128 * 64];
    __shared__ u16   Bs[128 * 64];

    int t = threadIdx.x;
    int lane = t & 63, w = t >> 6;
    int row0 = blockIdx.x * 128, col0 = blockIdx.y * 128;
    int wr = (w >> 1) * 64, wc = (w & 1) * 64;
    int qd = lane >> 4, md = lane & 15;

    f32x4 acc[4][4] = {};

    for (int kt = 0; kt < 256; kt += 64) {
#pragma unroll
        for (int u = 0; u < 8; ++u) {
            int chunk = w * 8 + u;
            int s = chunk * 64 + lane;
            int r = s >> 4, c = s & 15;
            gload16(Af + (size_t)(row0 + r) * 256 + kt + ((c ^ (r & 15)) * 4),
                    (char*)Asf + chunk * 1024);
        }
#pragma unroll
        for (int u = 0; u < 4; ++u) {
            int chunk = w * 4 + u;
            int s = chunk * 64 + lane;
            int r = s >> 3, c = s & 7;
            gload16(Wt + (size_t)(col0 + r) * 256 + kt + ((c ^ (r & 7)) * 8),
                    (char*)Bs + chunk * 1024);
        }
        __syncthreads();
#pragma unroll
        for (int ks = 0; ks < 64; ks += 32) {
            short8 af[4], bf[4];
#pragma unroll
            for (int i = 0; i < 4; ++i) {
                int ar = wr + i * 16 + md;
                int c0 = (ks >> 2) + qd * 2;
                int x = ar & 15;
                float4 fa0 = reinterpret_cast<const float4*>(Asf)[ar * 16 + (c0 ^ x)];
                float4 fa1 = reinterpret_cast<const float4*>(Asf)[ar * 16 + ((c0 + 1) ^ x)];
                af[i] = cvt8(fa0, fa1);
            }
#pragma unroll
            for (int j = 0; j < 4; ++j) {
                int br = wc + j * 16 + md;
                int slot = ((ks >> 3) + qd) ^ (br & 7);
                bf[j] = reinterpret_cast<const short8*>(Bs)[br * 8 + slot];
            }
#pragma unroll
            for (int i = 0; i < 4; ++i)
#pragma unroll
                for (int j = 0; j < 4; ++j)
                    acc[i][j] = __builtin_amdgcn_mfma_f32_16x16x32_bf16(
                        af[i], bf[j], acc[i][j], 0, 0, 0);
        }
        __syncthreads();
    }

#pragma unroll
    for (int i = 0; i < 4; ++i)
#pragma unroll
        for (int j = 0; j < 4; ++j) {
            int col = col0 + wc + j * 16 + md;
            float b = bias[col];
#pragma unroll
            for (int r = 0; r < 4; ++r) {
                int row = row0 + wr + i * 16 + qd * 4 + r;
                C[(size_t)row * 256 + col] = f2bf(acc[i][j][r] + b);
            }
        }
}

// ---------------------------------------------------------------------------
// gemm_out: f32 C = bf16 A @ Wt^T + bias. 64x128 tile. (R6 best)
// ---------------------------------------------------------------------------
__global__ __launch_bounds__(256) void gemm_out(
    const u16* __restrict__ Ab, const u16* __restrict__ Wt,
    const float* __restrict__ bias, float* __restrict__ Cout)
{
    __shared__ u16 As[64 * 64];
    __shared__ u16 Bs[128 * 64];

    int t = threadIdx.x;
    int lane = t & 63, w = t >> 6;
    int row0 = blockIdx.x * 64, col0 = blockIdx.y * 128;
    int wr = (w >> 1) * 32, wc = (w & 1) * 64;
    int qd = lane >> 4, md = lane & 15;

    f32x4 acc[2][4] = {};

    for (int kt = 0; kt < 256; kt += 64) {
#pragma unroll
        for (int u = 0; u < 2; ++u) {
            int chunk = w * 2 + u;
            int s = chunk * 64 + lane;
            int r = s >> 3, c = s & 7;
            gload16(Ab + (size_t)(row0 + r) * 256 + kt + ((c ^ (r & 7)) * 8),
                    (char*)As + chunk * 1024);
        }
#pragma unroll
        for (int u = 0; u < 4; ++u) {
            int chunk = w * 4 + u;
            int s = chunk * 64 + lane;
            int r = s >> 3, c = s & 7;
            gload16(Wt + (size_t)(col0 + r) * 256 + kt + ((c ^ (r & 7)) * 8),
                    (char*)Bs + chunk * 1024);
        }
        __syncthreads();
#pragma unroll
        for (int ks = 0; ks < 64; ks += 32) {
            short8 af[2], bf[4];
#pragma unroll
            for (int i = 0; i < 2; ++i) {
                int ar = wr + i * 16 + md;
                int slot = ((ks >> 3) + qd) ^ (ar & 7);
                af[i] = reinterpret_cast<const short8*>(As)[ar * 8 + slot];
            }
#pragma unroll
            for (int j = 0; j < 4; ++j) {
                int br = wc + j * 16 + md;
                int slot = ((ks >> 3) + qd) ^ (br & 7);
                bf[j] = reinterpret_cast<const short8*>(Bs)[br * 8 + slot];
            }
#pragma unroll
            for (int i = 0; i < 2; ++i)
#pragma unroll
                for (int j = 0; j < 4; ++j)
                    acc[i][j] = __builtin_amdgcn_mfma_f32_16x16x32_bf16(
                        af[i], bf[j], acc[i][j], 0, 0, 0);
        }
        __syncthreads();
    }

#pragma unroll
    for (int i = 0; i < 2; ++i)
#pragma unroll
        for (int j = 0; j < 4; ++j) {
            int col = col0 + wc + j * 16 + md;
            float b = bias[col];
#pragma unroll
            for (int r = 0; r < 4; ++r) {
                int row = row0 + wr + i * 16 + qd * 4 + r;
                Cout[(size_t)row * 256 + col] = acc[i][j][r] + b;
            }
        }
}

// ---------------------------------------------------------------------------
// attn (R8 best, 45.4 us): one wave per row, 2x8 batched K loads, register
// softmax, 2x8 batched V loads.
// ---------------------------------------------------------------------------
__global__ __launch_bounds__(256) void attn(
    const u16* __restrict__ Qh, const u16* __restrict__ Kh, const u16* __restrict__ Vh,
    const int* __restrict__ nbr, u16* __restrict__ AVb)
{
    __shared__ int jbs[4][32];

    int t = threadIdx.x;
    int w = t >> 6, lane = t & 63;
    int row = blockIdx.x * 4 + w;
    int b = row >> 13;
    int bbase = b << 13;

    int c8 = lane & 31;
    int jh = lane >> 5;

    if (lane < 32) {
        int ji = nbr[(size_t)row * 32 + lane];
        jbs[w][lane] = (bbase + ji) * 256;
    }

    float qf[8];
    {
        uint4 qw = *reinterpret_cast<const uint4*>(Qh + (size_t)row * 256 + c8 * 8);
        up2(qw.x, qf[0], qf[1]); up2(qw.y, qf[2], qf[3]);
        up2(qw.z, qf[4], qf[5]); up2(qw.w, qf[6], qf[7]);
    }

    float e16[16];
#pragma unroll
    for (int bb = 0; bb < 2; ++bb) {
        uint4 kw[8];
#pragma unroll
        for (int u = 0; u < 8; ++u) {
            int koff = jbs[w][jh * 16 + bb * 8 + u];
            kw[u] = *reinterpret_cast<const uint4*>(Kh + (size_t)koff + c8 * 8);
        }
#pragma unroll
        for (int u = 0; u < 8; ++u) {
            float k0, k1;
            float p = 0.f;
            up2(kw[u].x, k0, k1); p = fmaf(qf[0], k0, p); p = fmaf(qf[1], k1, p);
            up2(kw[u].y, k0, k1); p = fmaf(qf[2], k0, p); p = fmaf(qf[3], k1, p);
            up2(kw[u].z, k0, k1); p = fmaf(qf[4], k0, p); p = fmaf(qf[5], k1, p);
            up2(kw[u].w, k0, k1); p = fmaf(qf[6], k0, p); p = fmaf(qf[7], k1, p);
            p += __shfl_xor(p, 1);
            p += __shfl_xor(p, 2);
            e16[bb * 8 + u] = p * 0.0625f;
        }
    }

    float m = e16[0];
#pragma unroll
    for (int jj = 1; jj < 16; ++jj) m = fmaxf(m, e16[jj]);
    m = fmaxf(m, __shfl_xor(m, 32));
    float s = 0.f;
#pragma unroll
    for (int jj = 0; jj < 16; ++jj) { e16[jj] = __expf(e16[jj] - m); s += e16[jj]; }
    s += __shfl_xor(s, 32);
    float rs = 1.0f / s;
#pragma unroll
    for (int jj = 0; jj < 16; ++jj) e16[jj] *= rs;

    float acc[8] = {};
#pragma unroll
    for (int bb = 0; bb < 2; ++bb) {
        uint4 vv[8];
#pragma unroll
        for (int u = 0; u < 8; ++u) {
            int voff = jbs[w][jh * 16 + bb * 8 + u];
            vv[u] = *reinterpret_cast<const uint4*>(Vh + (size_t)voff + c8 * 8);
        }
#pragma unroll
        for (int u = 0; u < 8; ++u) {
            float v0, v1;
            float wgt = e16[bb * 8 + u];
            up2(vv[u].x, v0, v1); acc[0] = fmaf(wgt, v0, acc[0]); acc[1] = fmaf(wgt, v1, acc[1]);
            up2(vv[u].y, v0, v1); acc[2] = fmaf(wgt, v0, acc[2]); acc[3] = fmaf(wgt, v1, acc[3]);
            up2(vv[u].z, v0, v1); acc[4] = fmaf(wgt, v0, acc[4]); acc[5] = fmaf(wgt, v1, acc[5]);
            up2(vv[u].w, v0, v1); acc[6] = fmaf(wgt, v0, acc[6]); acc[7] = fmaf(wgt, v1, acc[7]);
        }
    }
#pragma unroll
    for (int u = 0; u < 8; ++u) acc[u] += __shfl_xor(acc[u], 32);

    if (lane < 32) {
        union { __hip_bfloat162 h[4]; uint4 u4; } o;
        o.h[0] = __float22bfloat162_rn(make_float2(acc[0], acc[1]));
        o.h[1] = __float22bfloat162_rn(make_float2(acc[2], acc[3]));
        o.h[2] = __float22bfloat162_rn(make_float2(acc[4], acc[5]));
        o.h[3] = __float22bfloat162_rn(make_float2(acc[6], acc[7]));
        *reinterpret_cast<uint4*>(AVb + (size_t)row * 256 + c8 * 8) = o.u4;
    }
}

// ---------------------------------------------------------------------------
extern "C" void kernel_launch(void* const* d_in, const int* in_sizes, int n_in,
                              void* d_out, int out_size, void* d_ws, size_t ws_size,
                              hipStream_t stream) {
    const float* Q   = (const float*)d_in[0];
    const float* K   = (const float*)d_in[1];
    const int*   nbr = (const int*)d_in[2];
    const float* Wq  = (const float*)d_in[3];
    const float* bq  = (const float*)d_in[4];
    const float* Wk  = (const float*)d_in[5];
    const float* bk  = (const float*)d_in[6];
    const float* Wv  = (const float*)d_in[7];
    const float* bv  = (const float*)d_in[8];
    const float* Wo  = (const float*)d_in[9];
    const float* bo  = (const float*)d_in[10];
    float* out = (float*)d_out;

    char* ws = (char*)d_ws;
    size_t off = 0;
    auto alloc = [&](size_t bytes) -> void* {
        void* p = ws + off;
        off += (bytes + 255) & ~(size_t)255;
        return p;
    };
    const size_t MN = 16384;
    u16* Wtq = (u16*)alloc(256 * 256 * 2);
    u16* Wtk = (u16*)alloc(256 * 256 * 2);
    u16* Wtv = (u16*)alloc(256 * 256 * 2);
    u16* Wto = (u16*)alloc(256 * 256 * 2);
    u16* Qh  = (u16*)alloc(MN * 256 * 2);
    u16* Kh  = (u16*)alloc(MN * 256 * 2);
    u16* Vh  = (u16*)alloc(MN * 256 * 2);
    u16* AVb = (u16*)alloc(MN * 256 * 2);

    wprep<<<dim3(4, 4, 4), 256, 0, stream>>>(Wq, Wk, Wv, Wo, Wtq, Wtk, Wtv, Wto);
    gemm_proj<<<dim3(128, 2, 3), 256, 0, stream>>>(Q, K, Wtq, Wtk, Wtv,
                                                   bq, bk, bv, Qh, Kh, Vh);
    attn<<<dim3(4096), 256, 0, stream>>>(Qh, Kh, Vh, nbr, AVb);
    gemm_out<<<dim3(256, 2), 256, 0, stream>>>(AVb, Wto, bo, out);
}

// Round 12
// 159.376 us; speedup vs baseline: 1.0678x; 1.0023x over previous
//
#include <hip/hip_runtime.h>
#include <hip/hip_bf16.h>
#include <stdint.h>

typedef unsigned short u16;
typedef __attribute__((ext_vector_type(8))) short short8;
typedef __attribute__((ext_vector_type(4))) float f32x4;

__device__ __forceinline__ u16 f2bf(float f) {
    union { float f; unsigned int i; } v; v.f = f;
    unsigned int b = v.i;
    return (u16)((b + 0x7FFFu + ((b >> 16) & 1u)) >> 16);
}

__device__ __forceinline__ short8 cvt8(float4 a, float4 b) {
    union { __hip_bfloat162 h[4]; short8 s; } u;
    u.h[0] = __float22bfloat162_rn(make_float2(a.x, a.y));
    u.h[1] = __float22bfloat162_rn(make_float2(a.z, a.w));
    u.h[2] = __float22bfloat162_rn(make_float2(b.x, b.y));
    u.h[3] = __float22bfloat162_rn(make_float2(b.z, b.w));
    return u.s;
}

typedef const __attribute__((address_space(1))) void* as1cv;
typedef __attribute__((address_space(3))) void* as3v;
__device__ __forceinline__ void gload16(const void* g, void* l) {
    __builtin_amdgcn_global_load_lds((as1cv)g, (as3v)l, 16, 0, 0);
}

__device__ __forceinline__ void up2(unsigned int v, float& lo, float& hi) {
    union { unsigned int i; float f; } a, b;
    a.i = v << 16; b.i = v & 0xffff0000u;
    lo = a.f; hi = b.f;
}

// ---------------------------------------------------------------------------
// wprep: weight convert fp32 -> bf16, transposed: Wt[n][k] = W[k][n]
// ---------------------------------------------------------------------------
__global__ __launch_bounds__(256) void wprep(
    const float* __restrict__ W0, const float* __restrict__ W1,
    const float* __restrict__ W2, const float* __restrict__ W3,
    u16* __restrict__ T0, u16* __restrict__ T1,
    u16* __restrict__ T2, u16* __restrict__ T3)
{
    const float* W = blockIdx.z == 0 ? W0 : blockIdx.z == 1 ? W1 : blockIdx.z == 2 ? W2 : W3;
    u16*        T  = blockIdx.z == 0 ? T0 : blockIdx.z == 1 ? T1 : blockIdx.z == 2 ? T2 : T3;
    __shared__ u16 ts[64][65];
    int k0 = blockIdx.x * 64, n0 = blockIdx.y * 64;
    int t = threadIdx.x;
    int r = t >> 2, cq = (t & 3) * 16;
    const float4* src = reinterpret_cast<const float4*>(W + (k0 + r) * 256 + n0 + cq);
    for (int u = 0; u < 4; ++u) {
        float4 v = src[u];
        int c = cq + u * 4;
        ts[r][c + 0] = f2bf(v.x); ts[r][c + 1] = f2bf(v.y);
        ts[r][c + 2] = f2bf(v.z); ts[r][c + 3] = f2bf(v.w);
    }
    __syncthreads();
    u16* dst = T + (n0 + r) * 256 + k0 + cq;
    for (int u = 0; u < 16; ++u) dst[u] = ts[cq + u][r];
}

// ---------------------------------------------------------------------------
// gemm_proj (R11): C_bf16 = cvt(A_fp32) @ Wt^T + bias. 128x128, BK=64,
// XOR-swizzled LDS, global_load_lds staging. grid (128,2,3).
// ---------------------------------------------------------------------------
__global__ __launch_bounds__(256) void gemm_proj(
    const float* __restrict__ Q, const float* __restrict__ K,
    const u16* __restrict__ Wtq, const u16* __restrict__ Wtk, const u16* __restrict__ Wtv,
    const float* __restrict__ bq, const float* __restrict__ bk, const float* __restrict__ bv,
    u16* __restrict__ Qh, u16* __restrict__ Kh, u16* __restrict__ Vh)
{
    int z = blockIdx.z;
    const float* Af   = (z == 0) ? Q   : K;
    const u16*   Wt   = (z == 0) ? Wtq : (z == 1) ? Wtk : Wtv;
    const float* bias = (z == 0) ? bq  : (z == 1) ? bk  : bv;
    u16*         C    = (z == 0) ? Qh  : (z == 1) ? Kh  : Vh;

    __shared__ float Asf[128 * 64];
    __shared__ u16   Bs[128 * 64];

    int t = threadIdx.x;
    int lane = t & 63, w = t >> 6;
    int row0 = blockIdx.x * 128, col0 = blockIdx.y * 128;
    int wr = (w >> 1) * 64, wc = (w & 1) * 64;
    int qd = lane >> 4, md = lane & 15;

    f32x4 acc[4][4] = {};

    for (int kt = 0; kt < 256; kt += 64) {
#pragma unroll
        for (int u = 0; u < 8; ++u) {
            int chunk = w * 8 + u;
            int s = chunk * 64 + lane;
            int r = s >> 4, c = s & 15;
            gload16(Af + (size_t)(row0 + r) * 256 + kt + ((c ^ (r & 15)) * 4),
                    (char*)Asf + chunk * 1024);
        }
#pragma unroll
        for (int u = 0; u < 4; ++u) {
            int chunk = w * 4 + u;
            int s = chunk * 64 + lane;
            int r = s >> 3, c = s & 7;
            gload16(Wt + (size_t)(col0 + r) * 256 + kt + ((c ^ (r & 7)) * 8),
                    (char*)Bs + chunk * 1024);
        }
        __syncthreads();
#pragma unroll
        for (int ks = 0; ks < 64; ks += 32) {
            short8 af[4], bf[4];
#pragma unroll
            for (int i = 0; i < 4; ++i) {
                int ar = wr + i * 16 + md;
                int c0 = (ks >> 2) + qd * 2;
                int x = ar & 15;
                float4 fa0 = reinterpret_cast<const float4*>(Asf)[ar * 16 + (c0 ^ x)];
                float4 fa1 = reinterpret_cast<const float4*>(Asf)[ar * 16 + ((c0 + 1) ^ x)];
                af[i] = cvt8(fa0, fa1);
            }
#pragma unroll
            for (int j = 0; j < 4; ++j) {
                int br = wc + j * 16 + md;
                int slot = ((ks >> 3) + qd) ^ (br & 7);
                bf[j] = reinterpret_cast<const short8*>(Bs)[br * 8 + slot];
            }
#pragma unroll
            for (int i = 0; i < 4; ++i)
#pragma unroll
                for (int j = 0; j < 4; ++j)
                    acc[i][j] = __builtin_amdgcn_mfma_f32_16x16x32_bf16(
                        af[i], bf[j], acc[i][j], 0, 0, 0);
        }
        __syncthreads();
    }

#pragma unroll
    for (int i = 0; i < 4; ++i)
#pragma unroll
        for (int j = 0; j < 4; ++j) {
            int col = col0 + wc + j * 16 + md;
            float b = bias[col];
#pragma unroll
            for (int r = 0; r < 4; ++r) {
                int row = row0 + wr + i * 16 + qd * 4 + r;
                C[(size_t)row * 256 + col] = f2bf(acc[i][j][r] + b);
            }
        }
}

// ---------------------------------------------------------------------------
// gemm_out: f32 C = bf16 A @ Wt^T + bias. 64x128 tile. (R11)
// ---------------------------------------------------------------------------
__global__ __launch_bounds__(256) void gemm_out(
    const u16* __restrict__ Ab, const u16* __restrict__ Wt,
    const float* __restrict__ bias, float* __restrict__ Cout)
{
    __shared__ u16 As[64 * 64];
    __shared__ u16 Bs[128 * 64];

    int t = threadIdx.x;
    int lane = t & 63, w = t >> 6;
    int row0 = blockIdx.x * 64, col0 = blockIdx.y * 128;
    int wr = (w >> 1) * 32, wc = (w & 1) * 64;
    int qd = lane >> 4, md = lane & 15;

    f32x4 acc[2][4] = {};

    for (int kt = 0; kt < 256; kt += 64) {
#pragma unroll
        for (int u = 0; u < 2; ++u) {
            int chunk = w * 2 + u;
            int s = chunk * 64 + lane;
            int r = s >> 3, c = s & 7;
            gload16(Ab + (size_t)(row0 + r) * 256 + kt + ((c ^ (r & 7)) * 8),
                    (char*)As + chunk * 1024);
        }
#pragma unroll
        for (int u = 0; u < 4; ++u) {
            int chunk = w * 4 + u;
            int s = chunk * 64 + lane;
            int r = s >> 3, c = s & 7;
            gload16(Wt + (size_t)(col0 + r) * 256 + kt + ((c ^ (r & 7)) * 8),
                    (char*)Bs + chunk * 1024);
        }
        __syncthreads();
#pragma unroll
        for (int ks = 0; ks < 64; ks += 32) {
            short8 af[2], bf[4];
#pragma unroll
            for (int i = 0; i < 2; ++i) {
                int ar = wr + i * 16 + md;
                int slot = ((ks >> 3) + qd) ^ (ar & 7);
                af[i] = reinterpret_cast<const short8*>(As)[ar * 8 + slot];
            }
#pragma unroll
            for (int j = 0; j < 4; ++j) {
                int br = wc + j * 16 + md;
                int slot = ((ks >> 3) + qd) ^ (br & 7);
                bf[j] = reinterpret_cast<const short8*>(Bs)[br * 8 + slot];
            }
#pragma unroll
            for (int i = 0; i < 2; ++i)
#pragma unroll
                for (int j = 0; j < 4; ++j)
                    acc[i][j] = __builtin_amdgcn_mfma_f32_16x16x32_bf16(
                        af[i], bf[j], acc[i][j], 0, 0, 0);
        }
        __syncthreads();
    }

#pragma unroll
    for (int i = 0; i < 2; ++i)
#pragma unroll
        for (int j = 0; j < 4; ++j) {
            int col = col0 + wc + j * 16 + md;
            float b = bias[col];
#pragma unroll
            for (int r = 0; r < 4; ++r) {
                int row = row0 + wr + i * 16 + qd * 4 + r;
                Cout[(size_t)row * 256 + col] = acc[i][j][r] + b;
            }
        }
}

// ---------------------------------------------------------------------------
// attn (R8 kernel + XCD-aware batch partitioning): one wave per row, 2x8
// batched K loads, register softmax, 2x8 batched V loads.
// Block swizzle: conjectured XCD = blockIdx % 8. XCDs 0-3 -> batch 0 rows,
// XCDs 4-7 -> batch 1 rows, halving each XCD's K/V L2 working set
// (16.8 MB -> 8.4 MB). Pure remap: coverage is 1:1 regardless of the real
// dispatch mapping, so correctness is unaffected.
// ---------------------------------------------------------------------------
__global__ __launch_bounds__(256) void attn(
    const u16* __restrict__ Qh, const u16* __restrict__ Kh, const u16* __restrict__ Vh,
    const int* __restrict__ nbr, u16* __restrict__ AVb)
{
    __shared__ int jbs[4][32];

    int t = threadIdx.x;
    int w = t >> 6, lane = t & 63;

    // XCD-aware row-group mapping
    int g = blockIdx.x & 7;
    int batch = g >> 2;                            // 0 for XCD 0-3, 1 for XCD 4-7
    int group = (blockIdx.x >> 3) * 4 + (g & 3);   // 0..2047 within batch
    int row = batch * 8192 + group * 4 + w;
    int b = batch;
    int bbase = b << 13;

    int c8 = lane & 31;
    int jh = lane >> 5;

    if (lane < 32) {
        int ji = nbr[(size_t)row * 32 + lane];
        jbs[w][lane] = (bbase + ji) * 256;
    }

    float qf[8];
    {
        uint4 qw = *reinterpret_cast<const uint4*>(Qh + (size_t)row * 256 + c8 * 8);
        up2(qw.x, qf[0], qf[1]); up2(qw.y, qf[2], qf[3]);
        up2(qw.z, qf[4], qf[5]); up2(qw.w, qf[6], qf[7]);
    }

    float e16[16];
#pragma unroll
    for (int bb = 0; bb < 2; ++bb) {
        uint4 kw[8];
#pragma unroll
        for (int u = 0; u < 8; ++u) {
            int koff = jbs[w][jh * 16 + bb * 8 + u];
            kw[u] = *reinterpret_cast<const uint4*>(Kh + (size_t)koff + c8 * 8);
        }
#pragma unroll
        for (int u = 0; u < 8; ++u) {
            float k0, k1;
            float p = 0.f;
            up2(kw[u].x, k0, k1); p = fmaf(qf[0], k0, p); p = fmaf(qf[1], k1, p);
            up2(kw[u].y, k0, k1); p = fmaf(qf[2], k0, p); p = fmaf(qf[3], k1, p);
            up2(kw[u].z, k0, k1); p = fmaf(qf[4], k0, p); p = fmaf(qf[5], k1, p);
            up2(kw[u].w, k0, k1); p = fmaf(qf[6], k0, p); p = fmaf(qf[7], k1, p);
            p += __shfl_xor(p, 1);
            p += __shfl_xor(p, 2);
            e16[bb * 8 + u] = p * 0.0625f;
        }
    }

    float m = e16[0];
#pragma unroll
    for (int jj = 1; jj < 16; ++jj) m = fmaxf(m, e16[jj]);
    m = fmaxf(m, __shfl_xor(m, 32));
    float s = 0.f;
#pragma unroll
    for (int jj = 0; jj < 16; ++jj) { e16[jj] = __expf(e16[jj] - m); s += e16[jj]; }
    s += __shfl_xor(s, 32);
    float rs = 1.0f / s;
#pragma unroll
    for (int jj = 0; jj < 16; ++jj) e16[jj] *= rs;

    float acc[8] = {};
#pragma unroll
    for (int bb = 0; bb < 2; ++bb) {
        uint4 vv[8];
#pragma unroll
        for (int u = 0; u < 8; ++u) {
            int voff = jbs[w][jh * 16 + bb * 8 + u];
            vv[u] = *reinterpret_cast<const uint4*>(Vh + (size_t)voff + c8 * 8);
        }
#pragma unroll
        for (int u = 0; u < 8; ++u) {
            float v0, v1;
            float wgt = e16[bb * 8 + u];
            up2(vv[u].x, v0, v1); acc[0] = fmaf(wgt, v0, acc[0]); acc[1] = fmaf(wgt, v1, acc[1]);
            up2(vv[u].y, v0, v1); acc[2] = fmaf(wgt, v0, acc[2]); acc[3] = fmaf(wgt, v1, acc[3]);
            up2(vv[u].z, v0, v1); acc[4] = fmaf(wgt, v0, acc[4]); acc[5] = fmaf(wgt, v1, acc[5]);
            up2(vv[u].w, v0, v1); acc[6] = fmaf(wgt, v0, acc[6]); acc[7] = fmaf(wgt, v1, acc[7]);
        }
    }
#pragma unroll
    for (int u = 0; u < 8; ++u) acc[u] += __shfl_xor(acc[u], 32);

    if (lane < 32) {
        union { __hip_bfloat162 h[4]; uint4 u4; } o;
        o.h[0] = __float22bfloat162_rn(make_float2(acc[0], acc[1]));
        o.h[1] = __float22bfloat162_rn(make_float2(acc[2], acc[3]));
        o.h[2] = __float22bfloat162_rn(make_float2(acc[4], acc[5]));
        o.h[3] = __float22bfloat162_rn(make_float2(acc[6], acc[7]));
        *reinterpret_cast<uint4*>(AVb + (size_t)row * 256 + c8 * 8) = o.u4;
    }
}

// ---------------------------------------------------------------------------
extern "C" void kernel_launch(void* const* d_in, const int* in_sizes, int n_in,
                              void* d_out, int out_size, void* d_ws, size_t ws_size,
                              hipStream_t stream) {
    const float* Q   = (const float*)d_in[0];
    const float* K   = (const float*)d_in[1];
    const int*   nbr = (const int*)d_in[2];
    const float* Wq  = (const float*)d_in[3];
    const float* bq  = (const float*)d_in[4];
    const float* Wk  = (const float*)d_in[5];
    const float* bk  = (const float*)d_in[6];
    const float* Wv  = (const float*)d_in[7];
    const float* bv  = (const float*)d_in[8];
    const float* Wo  = (const float*)d_in[9];
    const float* bo  = (const float*)d_in[10];
    float* out = (float*)d_out;

    char* ws = (char*)d_ws;
    size_t off = 0;
    auto alloc = [&](size_t bytes) -> void* {
        void* p = ws + off;
        off += (bytes + 255) & ~(size_t)255;
        return p;
    };
    const size_t MN = 16384;
    u16* Wtq = (u16*)alloc(256 * 256 * 2);
    u16* Wtk = (u16*)alloc(256 * 256 * 2);
    u16* Wtv = (u16*)alloc(256 * 256 * 2);
    u16* Wto = (u16*)alloc(256 * 256 * 2);
    u16* Qh  = (u16*)alloc(MN * 256 * 2);
    u16* Kh  = (u16*)alloc(MN * 256 * 2);
    u16* Vh  = (u16*)alloc(MN * 256 * 2);
    u16* AVb = (u16*)alloc(MN * 256 * 2);

    wprep<<<dim3(4, 4, 4), 256, 0, stream>>>(Wq, Wk, Wv, Wo, Wtq, Wtk, Wtv, Wto);
    gemm_proj<<<dim3(128, 2, 3), 256, 0, stream>>>(Q, K, Wtq, Wtk, Wtv,
                                                   bq, bk, bv, Qh, Kh, Vh);
    attn<<<dim3(4096), 256, 0, stream>>>(Qh, Kh, Vh, nbr, AVb);
    gemm_out<<<dim3(256, 2), 256, 0, stream>>>(AVb, Wto, bo, out);
}

// Round 14
// 153.395 us; speedup vs baseline: 1.1095x; 1.0390x over previous
//
#include <hip/hip_runtime.h>
#include <hip/hip_bf16.h>
#include <stdint.h>

typedef unsigned short u16;
typedef __attribute__((ext_vector_type(8))) short short8;
typedef __attribute__((ext_vector_type(4))) float f32x4;

__device__ __forceinline__ u16 f2bf(float f) {
    union { float f; unsigned int i; } v; v.f = f;
    unsigned int b = v.i;
    return (u16)((b + 0x7FFFu + ((b >> 16) & 1u)) >> 16);
}

__device__ __forceinline__ short8 cvt8(float4 a, float4 b) {
    union { __hip_bfloat162 h[4]; short8 s; } u;
    u.h[0] = __float22bfloat162_rn(make_float2(a.x, a.y));
    u.h[1] = __float22bfloat162_rn(make_float2(a.z, a.w));
    u.h[2] = __float22bfloat162_rn(make_float2(b.x, b.y));
    u.h[3] = __float22bfloat162_rn(make_float2(b.z, b.w));
    return u.s;
}

typedef const __attribute__((address_space(1))) void* as1cv;
typedef __attribute__((address_space(3))) void* as3v;
__device__ __forceinline__ void gload16(const void* g, void* l) {
    __builtin_amdgcn_global_load_lds((as1cv)g, (as3v)l, 16, 0, 0);
}

__device__ __forceinline__ void up2(unsigned int v, float& lo, float& hi) {
    union { unsigned int i; float f; } a, b;
    a.i = v << 16; b.i = v & 0xffff0000u;
    lo = a.f; hi = b.f;
}

// ---------------------------------------------------------------------------
// wprep: weight convert fp32 -> bf16, transposed: Wt[n][k] = W[k][n]
// ---------------------------------------------------------------------------
__global__ __launch_bounds__(256) void wprep(
    const float* __restrict__ W0, const float* __restrict__ W1,
    const float* __restrict__ W2, const float* __restrict__ W3,
    u16* __restrict__ T0, u16* __restrict__ T1,
    u16* __restrict__ T2, u16* __restrict__ T3)
{
    const float* W = blockIdx.z == 0 ? W0 : blockIdx.z == 1 ? W1 : blockIdx.z == 2 ? W2 : W3;
    u16*        T  = blockIdx.z == 0 ? T0 : blockIdx.z == 1 ? T1 : blockIdx.z == 2 ? T2 : T3;
    __shared__ u16 ts[64][65];
    int k0 = blockIdx.x * 64, n0 = blockIdx.y * 64;
    int t = threadIdx.x;
    int r = t >> 2, cq = (t & 3) * 16;
    const float4* src = reinterpret_cast<const float4*>(W + (k0 + r) * 256 + n0 + cq);
    for (int u = 0; u < 4; ++u) {
        float4 v = src[u];
        int c = cq + u * 4;
        ts[r][c + 0] = f2bf(v.x); ts[r][c + 1] = f2bf(v.y);
        ts[r][c + 2] = f2bf(v.z); ts[r][c + 3] = f2bf(v.w);
    }
    __syncthreads();
    u16* dst = T + (n0 + r) * 256 + k0 + cq;
    for (int u = 0; u < 16; ++u) dst[u] = ts[cq + u][r];
}

// ---------------------------------------------------------------------------
// gemm_proj (R11): C_bf16 = cvt(A_fp32) @ Wt^T + bias. 128x128, BK=64,
// XOR-swizzled LDS, global_load_lds staging. grid (128,2,3).
// ---------------------------------------------------------------------------
__global__ __launch_bounds__(256) void gemm_proj(
    const float* __restrict__ Q, const float* __restrict__ K,
    const u16* __restrict__ Wtq, const u16* __restrict__ Wtk, const u16* __restrict__ Wtv,
    const float* __restrict__ bq, const float* __restrict__ bk, const float* __restrict__ bv,
    u16* __restrict__ Qh, u16* __restrict__ Kh, u16* __restrict__ Vh)
{
    int z = blockIdx.z;
    const float* Af   = (z == 0) ? Q   : K;
    const u16*   Wt   = (z == 0) ? Wtq : (z == 1) ? Wtk : Wtv;
    const float* bias = (z == 0) ? bq  : (z == 1) ? bk  : bv;
    u16*         C    = (z == 0) ? Qh  : (z == 1) ? Kh  : Vh;

    __shared__ float Asf[128 * 64];
    __shared__ u16   Bs[128 * 64];

    int t = threadIdx.x;
    int lane = t & 63, w = t >> 6;
    int row0 = blockIdx.x * 128, col0 = blockIdx.y * 128;
    int wr = (w >> 1) * 64, wc = (w & 1) * 64;
    int qd = lane >> 4, md = lane & 15;

    f32x4 acc[4][4] = {};

    for (int kt = 0; kt < 256; kt += 64) {
#pragma unroll
        for (int u = 0; u < 8; ++u) {
            int chunk = w * 8 + u;
            int s = chunk * 64 + lane;
            int r = s >> 4, c = s & 15;
            gload16(Af + (size_t)(row0 + r) * 256 + kt + ((c ^ (r & 15)) * 4),
                    (char*)Asf + chunk * 1024);
        }
#pragma unroll
        for (int u = 0; u < 4; ++u) {
            int chunk = w * 4 + u;
            int s = chunk * 64 + lane;
            int r = s >> 3, c = s & 7;
            gload16(Wt + (size_t)(col0 + r) * 256 + kt + ((c ^ (r & 7)) * 8),
                    (char*)Bs + chunk * 1024);
        }
        __syncthreads();
#pragma unroll
        for (int ks = 0; ks < 64; ks += 32) {
            short8 af[4], bf[4];
#pragma unroll
            for (int i = 0; i < 4; ++i) {
                int ar = wr + i * 16 + md;
                int c0 = (ks >> 2) + qd * 2;
                int x = ar & 15;
                float4 fa0 = reinterpret_cast<const float4*>(Asf)[ar * 16 + (c0 ^ x)];
                float4 fa1 = reinterpret_cast<const float4*>(Asf)[ar * 16 + ((c0 + 1) ^ x)];
                af[i] = cvt8(fa0, fa1);
            }
#pragma unroll
            for (int j = 0; j < 4; ++j) {
                int br = wc + j * 16 + md;
                int slot = ((ks >> 3) + qd) ^ (br & 7);
                bf[j] = reinterpret_cast<const short8*>(Bs)[br * 8 + slot];
            }
#pragma unroll
            for (int i = 0; i < 4; ++i)
#pragma unroll
                for (int j = 0; j < 4; ++j)
                    acc[i][j] = __builtin_amdgcn_mfma_f32_16x16x32_bf16(
                        af[i], bf[j], acc[i][j], 0, 0, 0);
        }
        __syncthreads();
    }

#pragma unroll
    for (int i = 0; i < 4; ++i)
#pragma unroll
        for (int j = 0; j < 4; ++j) {
            int col = col0 + wc + j * 16 + md;
            float b = bias[col];
#pragma unroll
            for (int r = 0; r < 4; ++r) {
                int row = row0 + wr + i * 16 + qd * 4 + r;
                C[(size_t)row * 256 + col] = f2bf(acc[i][j][r] + b);
            }
        }
}

// ---------------------------------------------------------------------------
// gemm_out: f32 C = bf16 A @ Wt^T + bias. 64x128 tile. (R11)
// ---------------------------------------------------------------------------
__global__ __launch_bounds__(256) void gemm_out(
    const u16* __restrict__ Ab, const u16* __restrict__ Wt,
    const float* __restrict__ bias, float* __restrict__ Cout)
{
    __shared__ u16 As[64 * 64];
    __shared__ u16 Bs[128 * 64];

    int t = threadIdx.x;
    int lane = t & 63, w = t >> 6;
    int row0 = blockIdx.x * 64, col0 = blockIdx.y * 128;
    int wr = (w >> 1) * 32, wc = (w & 1) * 64;
    int qd = lane >> 4, md = lane & 15;

    f32x4 acc[2][4] = {};

    for (int kt = 0; kt < 256; kt += 64) {
#pragma unroll
        for (int u = 0; u < 2; ++u) {
            int chunk = w * 2 + u;
            int s = chunk * 64 + lane;
            int r = s >> 3, c = s & 7;
            gload16(Ab + (size_t)(row0 + r) * 256 + kt + ((c ^ (r & 7)) * 8),
                    (char*)As + chunk * 1024);
        }
#pragma unroll
        for (int u = 0; u < 4; ++u) {
            int chunk = w * 4 + u;
            int s = chunk * 64 + lane;
            int r = s >> 3, c = s & 7;
            gload16(Wt + (size_t)(col0 + r) * 256 + kt + ((c ^ (r & 7)) * 8),
                    (char*)Bs + chunk * 1024);
        }
        __syncthreads();
#pragma unroll
        for (int ks = 0; ks < 64; ks += 32) {
            short8 af[2], bf[4];
#pragma unroll
            for (int i = 0; i < 2; ++i) {
                int ar = wr + i * 16 + md;
                int slot = ((ks >> 3) + qd) ^ (ar & 7);
                af[i] = reinterpret_cast<const short8*>(As)[ar * 8 + slot];
            }
#pragma unroll
            for (int j = 0; j < 4; ++j) {
                int br = wc + j * 16 + md;
                int slot = ((ks >> 3) + qd) ^ (br & 7);
                bf[j] = reinterpret_cast<const short8*>(Bs)[br * 8 + slot];
            }
#pragma unroll
            for (int i = 0; i < 2; ++i)
#pragma unroll
                for (int j = 0; j < 4; ++j)
                    acc[i][j] = __builtin_amdgcn_mfma_f32_16x16x32_bf16(
                        af[i], bf[j], acc[i][j], 0, 0, 0);
        }
        __syncthreads();
    }

#pragma unroll
    for (int i = 0; i < 2; ++i)
#pragma unroll
        for (int j = 0; j < 4; ++j) {
            int col = col0 + wc + j * 16 + md;
            float b = bias[col];
#pragma unroll
            for (int r = 0; r < 4; ++r) {
                int row = row0 + wr + i * 16 + qd * 4 + r;
                Cout[(size_t)row * 256 + col] = acc[i][j][r] + b;
            }
        }
}

// shared row-mapping for the split attn kernels (XCD batch partitioning)
__device__ __forceinline__ int attn_row(int blk, int w) {
    int g = blk & 7;
    int batch = g >> 2;
    int group = (blk >> 3) * 4 + (g & 3);
    return batch * 8192 + group * 4 + w;
}

// ---------------------------------------------------------------------------
// attn_score: K-only pass (per-XCD gather set = 4 MiB, L2-sized).
// One wave per row. Scores per (head, nbr): e16[] in lane (c8, jh) is for
// head c8>>2, nbr jh*16+jj. Weights are PER-HEAD (8x32 per row): lanes with
// c8%4==0 stage all 8 heads x 2 halves into LDS; __syncthreads; coalesced
// 1 KB/wave store to Wgt[row][h][32] f32.
// ---------------------------------------------------------------------------
__global__ __launch_bounds__(256) void attn_score(
    const u16* __restrict__ Qh, const u16* __restrict__ Kh,
    const int* __restrict__ nbr, float* __restrict__ Wgt)
{
    __shared__ int jbs[4][32];
    __shared__ float wsm[4][256];

    int t = threadIdx.x;
    int w = t >> 6, lane = t & 63;
    int row = attn_row(blockIdx.x, w);
    int bbase = (row >> 13) << 13;

    int c8 = lane & 31;
    int jh = lane >> 5;

    if (lane < 32) {
        int ji = nbr[(size_t)row * 32 + lane];
        jbs[w][lane] = (bbase + ji) * 256;
    }

    float qf[8];
    {
        uint4 qw = *reinterpret_cast<const uint4*>(Qh + (size_t)row * 256 + c8 * 8);
        up2(qw.x, qf[0], qf[1]); up2(qw.y, qf[2], qf[3]);
        up2(qw.z, qf[4], qf[5]); up2(qw.w, qf[6], qf[7]);
    }

    float e16[16];
#pragma unroll
    for (int bb = 0; bb < 2; ++bb) {
        uint4 kw[8];
#pragma unroll
        for (int u = 0; u < 8; ++u) {
            int koff = jbs[w][jh * 16 + bb * 8 + u];
            kw[u] = *reinterpret_cast<const uint4*>(Kh + (size_t)koff + c8 * 8);
        }
#pragma unroll
        for (int u = 0; u < 8; ++u) {
            float k0, k1;
            float p = 0.f;
            up2(kw[u].x, k0, k1); p = fmaf(qf[0], k0, p); p = fmaf(qf[1], k1, p);
            up2(kw[u].y, k0, k1); p = fmaf(qf[2], k0, p); p = fmaf(qf[3], k1, p);
            up2(kw[u].z, k0, k1); p = fmaf(qf[4], k0, p); p = fmaf(qf[5], k1, p);
            up2(kw[u].w, k0, k1); p = fmaf(qf[6], k0, p); p = fmaf(qf[7], k1, p);
            p += __shfl_xor(p, 1);
            p += __shfl_xor(p, 2);
            e16[bb * 8 + u] = p * 0.0625f;
        }
    }

    // per-head softmax over 32 nbrs (16 local + cross-half via xor-32)
    float m = e16[0];
#pragma unroll
    for (int jj = 1; jj < 16; ++jj) m = fmaxf(m, e16[jj]);
    m = fmaxf(m, __shfl_xor(m, 32));
    float s = 0.f;
#pragma unroll
    for (int jj = 0; jj < 16; ++jj) { e16[jj] = __expf(e16[jj] - m); s += e16[jj]; }
    s += __shfl_xor(s, 32);
    float rs = 1.0f / s;

    // stage ALL heads' weights: writer lanes = one per (head, half)
    if ((c8 & 3) == 0) {
        int h = c8 >> 2;
#pragma unroll
        for (int jj = 0; jj < 16; ++jj)
            wsm[w][h * 32 + jh * 16 + jj] = e16[jj] * rs;
    }
    __syncthreads();

    // coalesced store: wave writes its row's 256 weights (1 KB)
    {
        float4 v = *reinterpret_cast<const float4*>(&wsm[w][lane * 4]);
        *reinterpret_cast<float4*>(Wgt + (size_t)row * 256 + lane * 4) = v;
    }
}

// ---------------------------------------------------------------------------
// attn_av: V-only pass (per-XCD gather set = 4 MiB, L2-sized).
// One wave per row: per-head weight load (4x float4, broadcast within
// head-group, written by the same XCD), 2x8 batched V gathers, accumulate,
// xor-32 combine, bf16 store.
// ---------------------------------------------------------------------------
__global__ __launch_bounds__(256) void attn_av(
    const u16* __restrict__ Vh, const int* __restrict__ nbr,
    const float* __restrict__ Wgt, u16* __restrict__ AVb)
{
    __shared__ int jbs[4][32];

    int t = threadIdx.x;
    int w = t >> 6, lane = t & 63;
    int row = attn_row(blockIdx.x, w);
    int bbase = (row >> 13) << 13;

    int c8 = lane & 31;
    int jh = lane >> 5;
    int h = c8 >> 2;

    if (lane < 32) {
        int ji = nbr[(size_t)row * 32 + lane];
        jbs[w][lane] = (bbase + ji) * 256;
    }

    // weights for (head h, half jh): 16 floats
    float e16[16];
    {
        const float4* wp = reinterpret_cast<const float4*>(
            Wgt + (size_t)row * 256 + h * 32 + jh * 16);
#pragma unroll
        for (int q = 0; q < 4; ++q) {
            float4 v = wp[q];
            e16[q * 4 + 0] = v.x; e16[q * 4 + 1] = v.y;
            e16[q * 4 + 2] = v.z; e16[q * 4 + 3] = v.w;
        }
    }

    float acc[8] = {};
#pragma unroll
    for (int bb = 0; bb < 2; ++bb) {
        uint4 vv[8];
#pragma unroll
        for (int u = 0; u < 8; ++u) {
            int voff = jbs[w][jh * 16 + bb * 8 + u];
            vv[u] = *reinterpret_cast<const uint4*>(Vh + (size_t)voff + c8 * 8);
        }
#pragma unroll
        for (int u = 0; u < 8; ++u) {
            float v0, v1;
            float wgt = e16[bb * 8 + u];
            up2(vv[u].x, v0, v1); acc[0] = fmaf(wgt, v0, acc[0]); acc[1] = fmaf(wgt, v1, acc[1]);
            up2(vv[u].y, v0, v1); acc[2] = fmaf(wgt, v0, acc[2]); acc[3] = fmaf(wgt, v1, acc[3]);
            up2(vv[u].z, v0, v1); acc[4] = fmaf(wgt, v0, acc[4]); acc[5] = fmaf(wgt, v1, acc[5]);
            up2(vv[u].w, v0, v1); acc[6] = fmaf(wgt, v0, acc[6]); acc[7] = fmaf(wgt, v1, acc[7]);
        }
    }
#pragma unroll
    for (int u = 0; u < 8; ++u) acc[u] += __shfl_xor(acc[u], 32);

    if (lane < 32) {
        union { __hip_bfloat162 h2[4]; uint4 u4; } o;
        o.h2[0] = __float22bfloat162_rn(make_float2(acc[0], acc[1]));
        o.h2[1] = __float22bfloat162_rn(make_float2(acc[2], acc[3]));
        o.h2[2] = __float22bfloat162_rn(make_float2(acc[4], acc[5]));
        o.h2[3] = __float22bfloat162_rn(make_float2(acc[6], acc[7]));
        *reinterpret_cast<uint4*>(AVb + (size_t)row * 256 + c8 * 8) = o.u4;
    }
}

// ---------------------------------------------------------------------------
extern "C" void kernel_launch(void* const* d_in, const int* in_sizes, int n_in,
                              void* d_out, int out_size, void* d_ws, size_t ws_size,
                              hipStream_t stream) {
    const float* Q   = (const float*)d_in[0];
    const float* K   = (const float*)d_in[1];
    const int*   nbr = (const int*)d_in[2];
    const float* Wq  = (const float*)d_in[3];
    const float* bq  = (const float*)d_in[4];
    const float* Wk  = (const float*)d_in[5];
    const float* bk  = (const float*)d_in[6];
    const float* Wv  = (const float*)d_in[7];
    const float* bv  = (const float*)d_in[8];
    const float* Wo  = (const float*)d_in[9];
    const float* bo  = (const float*)d_in[10];
    float* out = (float*)d_out;

    char* ws = (char*)d_ws;
    size_t off = 0;
    auto alloc = [&](size_t bytes) -> void* {
        void* p = ws + off;
        off += (bytes + 255) & ~(size_t)255;
        return p;
    };
    const size_t MN = 16384;
    u16* Wtq = (u16*)alloc(256 * 256 * 2);
    u16* Wtk = (u16*)alloc(256 * 256 * 2);
    u16* Wtv = (u16*)alloc(256 * 256 * 2);
    u16* Wto = (u16*)alloc(256 * 256 * 2);
    u16* Qh  = (u16*)alloc(MN * 256 * 2);
    u16* Kh  = (u16*)alloc(MN * 256 * 2);
    u16* Vh  = (u16*)alloc(MN * 256 * 2);
    u16* AVb = (u16*)alloc(MN * 256 * 2);
    float* Wgt = (float*)alloc(MN * 256 * 4);

    wprep<<<dim3(4, 4, 4), 256, 0, stream>>>(Wq, Wk, Wv, Wo, Wtq, Wtk, Wtv, Wto);
    gemm_proj<<<dim3(128, 2, 3), 256, 0, stream>>>(Q, K, Wtq, Wtk, Wtv,
                                                   bq, bk, bv, Qh, Kh, Vh);
    attn_score<<<dim3(4096), 256, 0, stream>>>(Qh, Kh, nbr, Wgt);
    attn_av<<<dim3(4096), 256, 0, stream>>>(Vh, nbr, Wgt, AVb);
    gemm_out<<<dim3(256, 2), 256, 0, stream>>>(AVb, Wto, bo, out);
}

// Round 15
// 151.776 us; speedup vs baseline: 1.1213x; 1.0107x over previous
//
#include <hip/hip_runtime.h>
#include <hip/hip_bf16.h>
#include <stdint.h>

typedef unsigned short u16;
typedef __attribute__((ext_vector_type(8))) short short8;
typedef __attribute__((ext_vector_type(4))) float f32x4;

__device__ __forceinline__ u16 f2bf(float f) {
    union { float f; unsigned int i; } v; v.f = f;
    unsigned int b = v.i;
    return (u16)((b + 0x7FFFu + ((b >> 16) & 1u)) >> 16);
}

__device__ __forceinline__ short8 cvt8(float4 a, float4 b) {
    union { __hip_bfloat162 h[4]; short8 s; } u;
    u.h[0] = __float22bfloat162_rn(make_float2(a.x, a.y));
    u.h[1] = __float22bfloat162_rn(make_float2(a.z, a.w));
    u.h[2] = __float22bfloat162_rn(make_float2(b.x, b.y));
    u.h[3] = __float22bfloat162_rn(make_float2(b.z, b.w));
    return u.s;
}

typedef const __attribute__((address_space(1))) void* as1cv;
typedef __attribute__((address_space(3))) void* as3v;
__device__ __forceinline__ void gload16(const void* g, void* l) {
    __builtin_amdgcn_global_load_lds((as1cv)g, (as3v)l, 16, 0, 0);
}

__device__ __forceinline__ void up2(unsigned int v, float& lo, float& hi) {
    union { unsigned int i; float f; } a, b;
    a.i = v << 16; b.i = v & 0xffff0000u;
    lo = a.f; hi = b.f;
}

// ---------------------------------------------------------------------------
// wprep: weight convert fp32 -> bf16, transposed: Wt[n][k] = W[k][n]
// ---------------------------------------------------------------------------
__global__ __launch_bounds__(256) void wprep(
    const float* __restrict__ W0, const float* __restrict__ W1,
    const float* __restrict__ W2, const float* __restrict__ W3,
    u16* __restrict__ T0, u16* __restrict__ T1,
    u16* __restrict__ T2, u16* __restrict__ T3)
{
    const float* W = blockIdx.z == 0 ? W0 : blockIdx.z == 1 ? W1 : blockIdx.z == 2 ? W2 : W3;
    u16*        T  = blockIdx.z == 0 ? T0 : blockIdx.z == 1 ? T1 : blockIdx.z == 2 ? T2 : T3;
    __shared__ u16 ts[64][65];
    int k0 = blockIdx.x * 64, n0 = blockIdx.y * 64;
    int t = threadIdx.x;
    int r = t >> 2, cq = (t & 3) * 16;
    const float4* src = reinterpret_cast<const float4*>(W + (k0 + r) * 256 + n0 + cq);
    for (int u = 0; u < 4; ++u) {
        float4 v = src[u];
        int c = cq + u * 4;
        ts[r][c + 0] = f2bf(v.x); ts[r][c + 1] = f2bf(v.y);
        ts[r][c + 2] = f2bf(v.z); ts[r][c + 3] = f2bf(v.w);
    }
    __syncthreads();
    u16* dst = T + (n0 + r) * 256 + k0 + cq;
    for (int u = 0; u < 16; ++u) dst[u] = ts[cq + u][r];
}

// ---------------------------------------------------------------------------
// gemm_proj (R11): C_bf16 = cvt(A_fp32) @ Wt^T + bias. 128x128, BK=64,
// XOR-swizzled LDS, global_load_lds staging. grid (128,2,3).
// ---------------------------------------------------------------------------
__global__ __launch_bounds__(256) void gemm_proj(
    const float* __restrict__ Q, const float* __restrict__ K,
    const u16* __restrict__ Wtq, const u16* __restrict__ Wtk, const u16* __restrict__ Wtv,
    const float* __restrict__ bq, const float* __restrict__ bk, const float* __restrict__ bv,
    u16* __restrict__ Qh, u16* __restrict__ Kh, u16* __restrict__ Vh)
{
    int z = blockIdx.z;
    const float* Af   = (z == 0) ? Q   : K;
    const u16*   Wt   = (z == 0) ? Wtq : (z == 1) ? Wtk : Wtv;
    const float* bias = (z == 0) ? bq  : (z == 1) ? bk  : bv;
    u16*         C    = (z == 0) ? Qh  : (z == 1) ? Kh  : Vh;

    __shared__ float Asf[128 * 64];
    __shared__ u16   Bs[128 * 64];

    int t = threadIdx.x;
    int lane = t & 63, w = t >> 6;
    int row0 = blockIdx.x * 128, col0 = blockIdx.y * 128;
    int wr = (w >> 1) * 64, wc = (w & 1) * 64;
    int qd = lane >> 4, md = lane & 15;

    f32x4 acc[4][4] = {};

    for (int kt = 0; kt < 256; kt += 64) {
#pragma unroll
        for (int u = 0; u < 8; ++u) {
            int chunk = w * 8 + u;
            int s = chunk * 64 + lane;
            int r = s >> 4, c = s & 15;
            gload16(Af + (size_t)(row0 + r) * 256 + kt + ((c ^ (r & 15)) * 4),
                    (char*)Asf + chunk * 1024);
        }
#pragma unroll
        for (int u = 0; u < 4; ++u) {
            int chunk = w * 4 + u;
            int s = chunk * 64 + lane;
            int r = s >> 3, c = s & 7;
            gload16(Wt + (size_t)(col0 + r) * 256 + kt + ((c ^ (r & 7)) * 8),
                    (char*)Bs + chunk * 1024);
        }
        __syncthreads();
#pragma unroll
        for (int ks = 0; ks < 64; ks += 32) {
            short8 af[4], bf[4];
#pragma unroll
            for (int i = 0; i < 4; ++i) {
                int ar = wr + i * 16 + md;
                int c0 = (ks >> 2) + qd * 2;
                int x = ar & 15;
                float4 fa0 = reinterpret_cast<const float4*>(Asf)[ar * 16 + (c0 ^ x)];
                float4 fa1 = reinterpret_cast<const float4*>(Asf)[ar * 16 + ((c0 + 1) ^ x)];
                af[i] = cvt8(fa0, fa1);
            }
#pragma unroll
            for (int j = 0; j < 4; ++j) {
                int br = wc + j * 16 + md;
                int slot = ((ks >> 3) + qd) ^ (br & 7);
                bf[j] = reinterpret_cast<const short8*>(Bs)[br * 8 + slot];
            }
#pragma unroll
            for (int i = 0; i < 4; ++i)
#pragma unroll
                for (int j = 0; j < 4; ++j)
                    acc[i][j] = __builtin_amdgcn_mfma_f32_16x16x32_bf16(
                        af[i], bf[j], acc[i][j], 0, 0, 0);
        }
        __syncthreads();
    }

#pragma unroll
    for (int i = 0; i < 4; ++i)
#pragma unroll
        for (int j = 0; j < 4; ++j) {
            int col = col0 + wc + j * 16 + md;
            float b = bias[col];
#pragma unroll
            for (int r = 0; r < 4; ++r) {
                int row = row0 + wr + i * 16 + qd * 4 + r;
                C[(size_t)row * 256 + col] = f2bf(acc[i][j][r] + b);
            }
        }
}

// ---------------------------------------------------------------------------
// gemm_out: f32 C = bf16 A @ Wt^T + bias. 64x128 tile. (R11)
// ---------------------------------------------------------------------------
__global__ __launch_bounds__(256) void gemm_out(
    const u16* __restrict__ Ab, const u16* __restrict__ Wt,
    const float* __restrict__ bias, float* __restrict__ Cout)
{
    __shared__ u16 As[64 * 64];
    __shared__ u16 Bs[128 * 64];

    int t = threadIdx.x;
    int lane = t & 63, w = t >> 6;
    int row0 = blockIdx.x * 64, col0 = blockIdx.y * 128;
    int wr = (w >> 1) * 32, wc = (w & 1) * 64;
    int qd = lane >> 4, md = lane & 15;

    f32x4 acc[2][4] = {};

    for (int kt = 0; kt < 256; kt += 64) {
#pragma unroll
        for (int u = 0; u < 2; ++u) {
            int chunk = w * 2 + u;
            int s = chunk * 64 + lane;
            int r = s >> 3, c = s & 7;
            gload16(Ab + (size_t)(row0 + r) * 256 + kt + ((c ^ (r & 7)) * 8),
                    (char*)As + chunk * 1024);
        }
#pragma unroll
        for (int u = 0; u < 4; ++u) {
            int chunk = w * 4 + u;
            int s = chunk * 64 + lane;
            int r = s >> 3, c = s & 7;
            gload16(Wt + (size_t)(col0 + r) * 256 + kt + ((c ^ (r & 7)) * 8),
                    (char*)Bs + chunk * 1024);
        }
        __syncthreads();
#pragma unroll
        for (int ks = 0; ks < 64; ks += 32) {
            short8 af[2], bf[4];
#pragma unroll
            for (int i = 0; i < 2; ++i) {
                int ar = wr + i * 16 + md;
                int slot = ((ks >> 3) + qd) ^ (ar & 7);
                af[i] = reinterpret_cast<const short8*>(As)[ar * 8 + slot];
            }
#pragma unroll
            for (int j = 0; j < 4; ++j) {
                int br = wc + j * 16 + md;
                int slot = ((ks >> 3) + qd) ^ (br & 7);
                bf[j] = reinterpret_cast<const short8*>(Bs)[br * 8 + slot];
            }
#pragma unroll
            for (int i = 0; i < 2; ++i)
#pragma unroll
                for (int j = 0; j < 4; ++j)
                    acc[i][j] = __builtin_amdgcn_mfma_f32_16x16x32_bf16(
                        af[i], bf[j], acc[i][j], 0, 0, 0);
        }
        __syncthreads();
    }

#pragma unroll
    for (int i = 0; i < 2; ++i)
#pragma unroll
        for (int j = 0; j < 4; ++j) {
            int col = col0 + wc + j * 16 + md;
            float b = bias[col];
#pragma unroll
            for (int r = 0; r < 4; ++r) {
                int row = row0 + wr + i * 16 + qd * 4 + r;
                Cout[(size_t)row * 256 + col] = acc[i][j][r] + b;
            }
        }
}

// shared row-mapping for the split attn kernels (XCD batch partitioning)
__device__ __forceinline__ int attn_row(int blk, int w) {
    int g = blk & 7;
    int batch = g >> 2;
    int group = (blk >> 3) * 4 + (g & 3);
    return batch * 8192 + group * 4 + w;
}

// ---------------------------------------------------------------------------
// attn_score: K-only pass (per-XCD gather set = 4 MiB, L2-sized).
// Per-head softmax; all 8 heads' weights staged in LDS, stored as BF16
// Wgt[row][h][32] (512 B/row) to halve the intermediate traffic.
// ---------------------------------------------------------------------------
__global__ __launch_bounds__(256) void attn_score(
    const u16* __restrict__ Qh, const u16* __restrict__ Kh,
    const int* __restrict__ nbr, u16* __restrict__ Wgt)
{
    __shared__ int jbs[4][32];
    __shared__ u16 wsm[4][256];

    int t = threadIdx.x;
    int w = t >> 6, lane = t & 63;
    int row = attn_row(blockIdx.x, w);
    int bbase = (row >> 13) << 13;

    int c8 = lane & 31;
    int jh = lane >> 5;

    if (lane < 32) {
        int ji = nbr[(size_t)row * 32 + lane];
        jbs[w][lane] = (bbase + ji) * 256;
    }

    float qf[8];
    {
        uint4 qw = *reinterpret_cast<const uint4*>(Qh + (size_t)row * 256 + c8 * 8);
        up2(qw.x, qf[0], qf[1]); up2(qw.y, qf[2], qf[3]);
        up2(qw.z, qf[4], qf[5]); up2(qw.w, qf[6], qf[7]);
    }

    float e16[16];
#pragma unroll
    for (int bb = 0; bb < 2; ++bb) {
        uint4 kw[8];
#pragma unroll
        for (int u = 0; u < 8; ++u) {
            int koff = jbs[w][jh * 16 + bb * 8 + u];
            kw[u] = *reinterpret_cast<const uint4*>(Kh + (size_t)koff + c8 * 8);
        }
#pragma unroll
        for (int u = 0; u < 8; ++u) {
            float k0, k1;
            float p = 0.f;
            up2(kw[u].x, k0, k1); p = fmaf(qf[0], k0, p); p = fmaf(qf[1], k1, p);
            up2(kw[u].y, k0, k1); p = fmaf(qf[2], k0, p); p = fmaf(qf[3], k1, p);
            up2(kw[u].z, k0, k1); p = fmaf(qf[4], k0, p); p = fmaf(qf[5], k1, p);
            up2(kw[u].w, k0, k1); p = fmaf(qf[6], k0, p); p = fmaf(qf[7], k1, p);
            p += __shfl_xor(p, 1);
            p += __shfl_xor(p, 2);
            e16[bb * 8 + u] = p * 0.0625f;
        }
    }

    // per-head softmax over 32 nbrs (16 local + cross-half via xor-32)
    float m = e16[0];
#pragma unroll
    for (int jj = 1; jj < 16; ++jj) m = fmaxf(m, e16[jj]);
    m = fmaxf(m, __shfl_xor(m, 32));
    float s = 0.f;
#pragma unroll
    for (int jj = 0; jj < 16; ++jj) { e16[jj] = __expf(e16[jj] - m); s += e16[jj]; }
    s += __shfl_xor(s, 32);
    float rs = 1.0f / s;

    // stage ALL heads' weights (bf16): writer lanes = one per (head, half)
    if ((c8 & 3) == 0) {
        int h = c8 >> 2;
#pragma unroll
        for (int jj = 0; jj < 16; ++jj)
            wsm[w][h * 32 + jh * 16 + jj] = f2bf(e16[jj] * rs);
    }
    __syncthreads();

    // coalesced store: wave writes its row's 256 bf16 weights (512 B)
    {
        uint2 v = *reinterpret_cast<const uint2*>(&wsm[w][lane * 4]);
        *reinterpret_cast<uint2*>(Wgt + (size_t)row * 256 + lane * 4) = v;
    }
}

// ---------------------------------------------------------------------------
// attn_av: V-only pass (per-XCD gather set = 4 MiB, L2-sized).
// Per-head bf16 weight load (2x uint2 = 32 B), 2x8 batched V gathers,
// accumulate, xor-32 combine, bf16 store.
// ---------------------------------------------------------------------------
__global__ __launch_bounds__(256) void attn_av(
    const u16* __restrict__ Vh, const int* __restrict__ nbr,
    const u16* __restrict__ Wgt, u16* __restrict__ AVb)
{
    __shared__ int jbs[4][32];

    int t = threadIdx.x;
    int w = t >> 6, lane = t & 63;
    int row = attn_row(blockIdx.x, w);
    int bbase = (row >> 13) << 13;

    int c8 = lane & 31;
    int jh = lane >> 5;
    int h = c8 >> 2;

    if (lane < 32) {
        int ji = nbr[(size_t)row * 32 + lane];
        jbs[w][lane] = (bbase + ji) * 256;
    }

    // weights for (head h, half jh): 16 bf16 -> f32
    float e16[16];
    {
        const uint4* wp = reinterpret_cast<const uint4*>(
            Wgt + (size_t)row * 256 + h * 32 + jh * 16);
        uint4 v = wp[0];
        up2(v.x, e16[0], e16[1]);  up2(v.y, e16[2], e16[3]);
        up2(v.z, e16[4], e16[5]);  up2(v.w, e16[6], e16[7]);
        v = wp[1];
        up2(v.x, e16[8], e16[9]);  up2(v.y, e16[10], e16[11]);
        up2(v.z, e16[12], e16[13]); up2(v.w, e16[14], e16[15]);
    }

    float acc[8] = {};
#pragma unroll
    for (int bb = 0; bb < 2; ++bb) {
        uint4 vv[8];
#pragma unroll
        for (int u = 0; u < 8; ++u) {
            int voff = jbs[w][jh * 16 + bb * 8 + u];
            vv[u] = *reinterpret_cast<const uint4*>(Vh + (size_t)voff + c8 * 8);
        }
#pragma unroll
        for (int u = 0; u < 8; ++u) {
            float v0, v1;
            float wgt = e16[bb * 8 + u];
            up2(vv[u].x, v0, v1); acc[0] = fmaf(wgt, v0, acc[0]); acc[1] = fmaf(wgt, v1, acc[1]);
            up2(vv[u].y, v0, v1); acc[2] = fmaf(wgt, v0, acc[2]); acc[3] = fmaf(wgt, v1, acc[3]);
            up2(vv[u].z, v0, v1); acc[4] = fmaf(wgt, v0, acc[4]); acc[5] = fmaf(wgt, v1, acc[5]);
            up2(vv[u].w, v0, v1); acc[6] = fmaf(wgt, v0, acc[6]); acc[7] = fmaf(wgt, v1, acc[7]);
        }
    }
#pragma unroll
    for (int u = 0; u < 8; ++u) acc[u] += __shfl_xor(acc[u], 32);

    if (lane < 32) {
        union { __hip_bfloat162 h2[4]; uint4 u4; } o;
        o.h2[0] = __float22bfloat162_rn(make_float2(acc[0], acc[1]));
        o.h2[1] = __float22bfloat162_rn(make_float2(acc[2], acc[3]));
        o.h2[2] = __float22bfloat162_rn(make_float2(acc[4], acc[5]));
        o.h2[3] = __float22bfloat162_rn(make_float2(acc[6], acc[7]));
        *reinterpret_cast<uint4*>(AVb + (size_t)row * 256 + c8 * 8) = o.u4;
    }
}

// ---------------------------------------------------------------------------
extern "C" void kernel_launch(void* const* d_in, const int* in_sizes, int n_in,
                              void* d_out, int out_size, void* d_ws, size_t ws_size,
                              hipStream_t stream) {
    const float* Q   = (const float*)d_in[0];
    const float* K   = (const float*)d_in[1];
    const int*   nbr = (const int*)d_in[2];
    const float* Wq  = (const float*)d_in[3];
    const float* bq  = (const float*)d_in[4];
    const float* Wk  = (const float*)d_in[5];
    const float* bk  = (const float*)d_in[6];
    const float* Wv  = (const float*)d_in[7];
    const float* bv  = (const float*)d_in[8];
    const float* Wo  = (const float*)d_in[9];
    const float* bo  = (const float*)d_in[10];
    float* out = (float*)d_out;

    char* ws = (char*)d_ws;
    size_t off = 0;
    auto alloc = [&](size_t bytes) -> void* {
        void* p = ws + off;
        off += (bytes + 255) & ~(size_t)255;
        return p;
    };
    const size_t MN = 16384;
    u16* Wtq = (u16*)alloc(256 * 256 * 2);
    u16* Wtk = (u16*)alloc(256 * 256 * 2);
    u16* Wtv = (u16*)alloc(256 * 256 * 2);
    u16* Wto = (u16*)alloc(256 * 256 * 2);
    u16* Qh  = (u16*)alloc(MN * 256 * 2);
    u16* Kh  = (u16*)alloc(MN * 256 * 2);
    u16* Vh  = (u16*)alloc(MN * 256 * 2);
    u16* AVb = (u16*)alloc(MN * 256 * 2);
    u16* Wgt = (u16*)alloc(MN * 256 * 2);

    wprep<<<dim3(4, 4, 4), 256, 0, stream>>>(Wq, Wk, Wv, Wo, Wtq, Wtk, Wtv, Wto);
    gemm_proj<<<dim3(128, 2, 3), 256, 0, stream>>>(Q, K, Wtq, Wtk, Wtv,
                                                   bq, bk, bv, Qh, Kh, Vh);
    attn_score<<<dim3(4096), 256, 0, stream>>>(Qh, Kh, nbr, Wgt);
    attn_av<<<dim3(4096), 256, 0, stream>>>(Vh, nbr, Wgt, AVb);
    gemm_out<<<dim3(256, 2), 256, 0, stream>>>(AVb, Wto, bo, out);
}